// Round 4
// baseline (1862.498 us; speedup 1.0000x reference)
//
#include <hip/hip_runtime.h>
#include <hip/hip_bf16.h>

typedef __bf16 bf16x8 __attribute__((ext_vector_type(8)));
typedef float  f32x4  __attribute__((ext_vector_type(4)));
typedef float  f32x2  __attribute__((ext_vector_type(2)));
typedef unsigned int u32x4 __attribute__((ext_vector_type(4)));
typedef unsigned short ushort_t;
static_assert(sizeof(bf16x8) == 16, "bf16x8 must be 16B");

#define DEV __device__ __forceinline__

DEV f32x4 mfma16(bf16x8 a, bf16x8 b, f32x4 c) {
    return __builtin_amdgcn_mfma_f32_16x16x32_bf16(a, b, c, 0, 0, 0);
}
DEV f32x4 mfma8(long a, long b, f32x4 c) {
    return __builtin_amdgcn_mfma_f32_16x16x32_fp8_fp8(a, b, c, 0, 0, 0);
}
DEV float sigm(float x)   { return 1.0f / (1.0f + __expf(-x)); }
DEV float tanh_f(float x) { return 2.0f / (1.0f + __expf(-2.0f * x)) - 1.0f; }

// async global->LDS, 16B per lane; lds dest must be wave-uniform base (+lane*16)
DEV void glds16(const __hip_bfloat16* g, __hip_bfloat16* l) {
    __builtin_amdgcn_global_load_lds(
        (const __attribute__((address_space(1))) unsigned int*)g,
        (__attribute__((address_space(3))) unsigned int*)l, 16, 0, 0);
}

DEV unsigned char f32_to_fp8(float v) {
    int p = __builtin_amdgcn_cvt_pk_fp8_f32(v, v, 0, false);
    return (unsigned char)(p & 0xFF);
}

// ---------------- dtype detection: 1 = inputs are bf16, 0 = inputs are fp32 --
__global__ __launch_bounds__(128) void kdetect(const unsigned int* __restrict__ raw,
                                               int* __restrict__ mode) {
    __shared__ int cnt;
    if (threadIdx.x == 0) cnt = 0;
    __syncthreads();
    unsigned int w = raw[threadIdx.x];
    unsigned short lo = (unsigned short)(w & 0xFFFFu);
    unsigned int f32bits = ((unsigned int)lo) << 16;
    float v;
    __builtin_memcpy(&v, &f32bits, 4);
    float a = fabsf(v);
    if (a >= 1e-4f && a <= 1.0f) atomicAdd(&cnt, 1);
    __syncthreads();
    if (threadIdx.x == 0) *mode = (cnt >= 64) ? 1 : 0;
}

__global__ __launch_bounds__(256) void kcvt_bf16(const void* __restrict__ src,
                                                 __hip_bfloat16* __restrict__ dst,
                                                 int n, const int* __restrict__ mode) {
    int i = blockIdx.x * 256 + threadIdx.x;
    if (i >= n) return;
    if (*mode) dst[i] = ((const __hip_bfloat16*)src)[i];
    else       dst[i] = __float2bfloat16(((const float*)src)[i]);
}

__global__ __launch_bounds__(256) void kcvt_f32(const void* __restrict__ src,
                                                float* __restrict__ dst,
                                                int n, const int* __restrict__ mode) {
    int i = blockIdx.x * 256 + threadIdx.x;
    if (i >= n) return;
    if (*mode) dst[i] = __bfloat162float(((const __hip_bfloat16*)src)[i]);
    else       dst[i] = ((const float*)src)[i];
}

// --------- tiled transpose + convert: out_bf16[c][r] = (bf16)in[r][c] --------
__global__ __launch_bounds__(256) void ktranspose_cvt(const void* __restrict__ src,
                                                      __hip_bfloat16* __restrict__ out,
                                                      int R, int C,
                                                      const int* __restrict__ mode) {
    __shared__ float tile[64][65];
    int c0 = blockIdx.x * 64, r0 = blockIdx.y * 64;
    int tx = threadIdx.x & 63, ty = threadIdx.x >> 6;
    int m = *mode;
#pragma unroll
    for (int i = ty; i < 64; i += 4) {
        size_t ix = (size_t)(r0 + i) * C + (c0 + tx);
        tile[i][tx] = m ? __bfloat162float(((const __hip_bfloat16*)src)[ix])
                        : ((const float*)src)[ix];
    }
    __syncthreads();
#pragma unroll
    for (int i = ty; i < 64; i += 4)
        out[(size_t)(c0 + i) * R + (r0 + tx)] = __float2bfloat16(tile[tx][i]);
}

// ---- fragment-order pack: dst[((n>>4)*(K/8) + k8)*128 + (n&15)*8 + (k&7)] ---
// Makes a wave's MFMA B-fragment load (16 rows x 8 k, lane=(r16,quad)) one
// fully-coalesced 1KB burst.
__global__ __launch_bounds__(256) void kpack_frag(const __hip_bfloat16* __restrict__ src,
                                                  __hip_bfloat16* __restrict__ dst,
                                                  int N, int K) {
    int id = blockIdx.x * 256 + threadIdx.x;   // one bf16x8 per thread
    int kb8 = K >> 3;
    int n = id / kb8, kb = id % kb8;
    if (n >= N) return;
    bf16x8 v = *(const bf16x8*)(src + (size_t)n * K + (size_t)kb * 8);
    *(bf16x8*)(dst + ((size_t)(n >> 4) * kb8 + kb) * 128 + (size_t)(n & 15) * 8) = v;
}

// ------ prep: G tables, gate-interleaved: G[dh][v][u<512][g<4] = E@Wi (+b) ---
__global__ __launch_bounds__(256) void kprep_gtab(
    const __hip_bfloat16* __restrict__ E,    // [128][128]
    const __hip_bfloat16* __restrict__ WiT,  // [2][2048][256]
    const float* __restrict__ bF,
    const float* __restrict__ bB,
    float* __restrict__ G)                   // [4][128][512][4]
{
    int dh = blockIdx.x >> 6;
    int dir = dh >> 1, half = dh & 1;
    int m0 = ((blockIdx.x >> 5) & 1) * 64;
    int n0 = (blockIdx.x & 31) * 64;
    int lane = threadIdx.x & 63, wid = threadIdx.x >> 6;
    int wrow = wid >> 1, wcol = wid & 1;
    int r16 = lane & 15, quad = lane >> 4;

    f32x4 acc[2][2] = {};
    const __hip_bfloat16* Ap = E + (size_t)(m0 + wrow * 32 + r16) * 128 + quad * 8;
    const __hip_bfloat16* Bp = WiT + (size_t)dir * 2048 * 256
                             + (size_t)(n0 + wcol * 32 + r16) * 256 + half * 128 + quad * 8;
#pragma unroll
    for (int kb = 0; kb < 128; kb += 32) {
        bf16x8 a0 = *(const bf16x8*)(Ap + kb);
        bf16x8 a1 = *(const bf16x8*)(Ap + 16 * 128 + kb);
        bf16x8 b0 = *(const bf16x8*)(Bp + kb);
        bf16x8 b1 = *(const bf16x8*)(Bp + 16 * 256 + kb);
        acc[0][0] = mfma16(a0, b0, acc[0][0]);
        acc[0][1] = mfma16(a0, b1, acc[0][1]);
        acc[1][0] = mfma16(a1, b0, acc[1][0]);
        acc[1][1] = mfma16(a1, b1, acc[1][1]);
    }
    const float* bias = dir ? bB : bF;
    float* Gt = G + (size_t)dh * 128 * 2048;
#pragma unroll
    for (int rt = 0; rt < 2; rt++)
#pragma unroll
        for (int ct = 0; ct < 2; ct++)
#pragma unroll
            for (int r = 0; r < 4; r++) {
                int mm = m0 + wrow * 32 + rt * 16 + quad * 4 + r;
                int j = n0 + wcol * 32 + ct * 16 + r16;
                float v = acc[rt][ct][r];
                if (half == 0) v += bias[j];
                int g = j >> 9, u = j & 511;
                Gt[((size_t)mm * 512 + u) * 4 + g] = v;
            }
}

// ---------------- prep: VX[t][j] = field_emb @ v_Wi + v_b --------------------
__global__ __launch_bounds__(256) void kprep_vx(
    const __hip_bfloat16* __restrict__ fe,    // [32][1024]
    const __hip_bfloat16* __restrict__ vWiT,  // [4096][1024]
    const float* __restrict__ vb,             // [4096]
    float* __restrict__ VX)                   // [32][4096]
{
    int n0 = blockIdx.x * 128;
    int lane = threadIdx.x & 63, wid = threadIdx.x >> 6;
    int r16 = lane & 15, quad = lane >> 4;
    f32x4 acc[2][2] = {};
    const __hip_bfloat16* Ap = fe + (size_t)r16 * 1024 + quad * 8;
    const __hip_bfloat16* Bp = vWiT + (size_t)(n0 + wid * 32 + r16) * 1024 + quad * 8;
    for (int kb = 0; kb < 1024; kb += 32) {
        bf16x8 a0 = *(const bf16x8*)(Ap + kb);
        bf16x8 a1 = *(const bf16x8*)(Ap + 16 * 1024 + kb);
        bf16x8 b0 = *(const bf16x8*)(Bp + kb);
        bf16x8 b1 = *(const bf16x8*)(Bp + 16 * 1024 + kb);
        acc[0][0] = mfma16(a0, b0, acc[0][0]);
        acc[0][1] = mfma16(a0, b1, acc[0][1]);
        acc[1][0] = mfma16(a1, b0, acc[1][0]);
        acc[1][1] = mfma16(a1, b1, acc[1][1]);
    }
#pragma unroll
    for (int rt = 0; rt < 2; rt++)
#pragma unroll
        for (int ct = 0; ct < 2; ct++)
#pragma unroll
            for (int r = 0; r < 4; r++) {
                int m = rt * 16 + quad * 4 + r;
                int j = n0 + wid * 32 + ct * 16 + r16;
                VX[(size_t)m * 4096 + j] = acc[rt][ct][r] + vb[j];
            }
}

// ======== encoder LSTM step: 256 blocks (dir x 16 mt x 8 us), 64m x 64u ======
// A (h) staged once to LDS (chunk-XOR swizzle, 1 barrier/step); B (weights)
// read directly global->VGPR from fragment-packed WhP (1KB coalesced bursts).
// No cross-wave B reuse exists, so LDS-staging B was pure overhead.
__global__ __launch_bounds__(512, 1) void kenc_step(
    int t,
    const __hip_bfloat16* __restrict__ WhP,   // packed [2][128 pan][64 kb][16][8]
    const float* __restrict__ Gtab,           // [4][128][512][4]
    const int* __restrict__ exs,
    const int* __restrict__ cls,
    const __hip_bfloat16* __restrict__ h_in,  // [2][1024][512]
    __hip_bfloat16* __restrict__ h_out,
    float* __restrict__ c_st,                 // [2][1024][512]
    unsigned char* __restrict__ ctx8)         // [64][256][4][1024] fp8 (x16)
{
    __shared__ __align__(16) __hip_bfloat16 sA[64 * 512];   // 64KB

    int bid = blockIdx.x;
    int dir = bid >> 7;
    int mt  = (bid >> 3) & 15;
    int us  = bid & 7;
    int l = dir ? (63 - t) : t;
    int m0 = mt * 64, u0 = us * 64;

    int lane = threadIdx.x & 63, w = threadIdx.x >> 6;   // 8 waves
    int wm = w >> 2, wu = w & 3;
    int r16 = lane & 15, quad = lane >> 4;

    const __hip_bfloat16* Ab = h_in + (size_t)dir * 1024 * 512;
    const __hip_bfloat16* Bp = WhP + (size_t)dir * 2048 * 512;

    // stage A: 64 rows x 512; row r's 16B-chunk c holds global chunk c^(r&7)
#pragma unroll
    for (int c = 0; c < 8; c++) {
        int r = w * 8 + c;
        glds16(Ab + (size_t)(m0 + r) * 512 + ((lane ^ (r & 7)) * 8), &sA[r * 512]);
    }

    // B fragment pointers: panel = g*32 + us*4 + wu, row-in-panel = r16
    const __hip_bfloat16* Bg[4];
#pragma unroll
    for (int g = 0; g < 4; g++)
        Bg[g] = Bp + ((size_t)(g * 32 + us * 4 + wu) * 64 + quad) * 128 + r16 * 8;

    f32x4 acc[4][2] = {};  // [gate][mi]
    __syncthreads();

    const int key = r16 & 7;
#pragma unroll 4
    for (int kk = 0; kk < 16; kk++) {
        bf16x8 bv[4];
#pragma unroll
        for (int g = 0; g < 4; g++)
            bv[g] = *(const bf16x8*)(Bg[g] + kk * 512);
        bf16x8 a[2];
#pragma unroll
        for (int mi = 0; mi < 2; mi++)
            a[mi] = *(const bf16x8*)&sA[(wm * 32 + mi * 16 + r16) * 512
                                        + (((kk * 4 + quad) ^ key) * 8)];
#pragma unroll
        for (int g = 0; g < 4; g++)
#pragma unroll
            for (int mi = 0; mi < 2; mi++)
                acc[g][mi] = mfma16(a[mi], bv[g], acc[g][mi]);
    }

    // epilogue: thread owns u = u0 + wu*16 + r16, 8 m's
    int u = u0 + wu * 16 + r16;
    size_t cbase = (size_t)dir * 1024 * 512;
    const float* GeT = Gtab + (size_t)(dir * 2) * 128 * 2048;
    const float* GcT = GeT + 128 * 2048;
#pragma unroll
    for (int mi = 0; mi < 2; mi++)
#pragma unroll
        for (int r = 0; r < 4; r++) {
            int m = m0 + wm * 32 + mi * 16 + quad * 4 + r;
            int vE = exs[l * 1024 + m], vC = cls[l * 1024 + m];
            f32x4 ge = *(const f32x4*)&GeT[((size_t)vE * 512 + u) * 4];
            f32x4 gc = *(const f32x4*)&GcT[((size_t)vC * 512 + u) * 4];
            float gi = acc[0][mi][r] + ge[0] + gc[0];
            float gf = acc[1][mi][r] + ge[1] + gc[1];
            float gg = acc[2][mi][r] + ge[2] + gc[2];
            float go = acc[3][mi][r] + ge[3] + gc[3];
            size_t cix = cbase + (size_t)m * 512 + u;
            float cn = sigm(gf) * c_st[cix] + sigm(gi) * tanh_f(gg);
            c_st[cix] = cn;
            float hn = sigm(go) * tanh_f(cn);
            h_out[cix] = __float2bfloat16(hn);
            ctx8[(((size_t)l * 256 + (m >> 2)) * 4 + (m & 3)) * 1024 + dir * 512 + u]
                = f32_to_fp8(hn * 16.0f);
        }
}

// ---- fp8 ctx transpose: ctxT8[b4n][e][l] = ctx8[l][b4n][e] ------------------
__global__ __launch_bounds__(256) void ktrans8(const unsigned char* __restrict__ ctx8,
                                               unsigned char* __restrict__ ctxT8) {
    __shared__ unsigned int tile[64][17];   // 64 l-rows x 64 e-bytes (16 u32 + pad)
    int b4n = blockIdx.x;                   // 0..1023
    int e0 = blockIdx.y * 64;               // e-tile
    int tid = threadIdx.x;
#pragma unroll
    for (int pass = 0; pass < 4; pass++) {
        int idx = pass * 256 + tid;
        int l = idx >> 4, c = idx & 15;
        tile[l][c] = *(const unsigned int*)(ctx8 + (size_t)l * (1024 * 1024)
                                            + (size_t)b4n * 1024 + e0 + c * 4);
    }
    __syncthreads();
    const unsigned char* tb = (const unsigned char*)tile;
#pragma unroll
    for (int pass = 0; pass < 4; pass++) {
        int idx = pass * 256 + tid;
        int e = idx >> 4, c = idx & 15;
        unsigned int v = 0;
#pragma unroll
        for (int j = 0; j < 4; j++) {
            unsigned int byte = tb[(size_t)(c * 4 + j) * 68 + e];
            v |= byte << (8 * j);
        }
        *(unsigned int*)(ctxT8 + ((size_t)b4n * 1024 + e0 + e) * 64 + c * 4) = v;
    }
}

// ======== decoder fused GEMM: cell (0..127: 32m x 64u) + q (128..255) ========
// Same B-direct scheme: A (h_in 32x1024) staged once, 1 barrier; B from
// fragment-packed vWhP / WattnP.
__global__ __launch_bounds__(256, 2) void kdec_gemm(
    int t,
    const __hip_bfloat16* __restrict__ vWhP,   // packed [256 pan][128 kb][16][8]
    const __hip_bfloat16* __restrict__ WattnP, // packed [64 pan][128 kb][16][8]
    const float* __restrict__ VX,              // [32][4096]
    const __hip_bfloat16* __restrict__ h_in,   // [256][1024]  (h_t = hAll[t])
    __hip_bfloat16* __restrict__ h_out,        // [256][1024]  (hAll[t+1])
    float* __restrict__ c_st,                  // [256][1024]
    float* __restrict__ qout)                  // [256][1024]  (qall[t])
{
    __shared__ __align__(16) __hip_bfloat16 sA[32 * 1024];   // 64KB

    int bid = blockIdx.x;
    int lane = threadIdx.x & 63, w = threadIdx.x >> 6;
    int r16 = lane & 15, quad = lane >> 4;
    bool cellp = bid < 128;
    int b2 = cellp ? bid : bid - 128;
    int m0 = (b2 >> 4) * 32, n0 = (b2 & 15) * 64;

    // stage A: 32 rows x 1024 (half-row per glds16); chunk c^(r&7) swizzle
#pragma unroll
    for (int c = 0; c < 16; c++) {
        int idx = w * 16 + c;
        int r = idx >> 1, hh = idx & 1;
        glds16(h_in + (size_t)(m0 + r) * 1024 + hh * 512 + ((lane ^ (r & 7)) * 8),
               &sA[r * 1024 + hh * 512]);
    }
    __syncthreads();
    const int key = r16 & 7;

    if (cellp) {
        const __hip_bfloat16* Bg[4];
#pragma unroll
        for (int g = 0; g < 4; g++)
            Bg[g] = vWhP + ((size_t)(g * 64 + (b2 & 15) * 4 + w) * 128 + quad) * 128
                  + r16 * 8;
        f32x4 acc[4][2] = {};
#pragma unroll 4
        for (int kk = 0; kk < 32; kk++) {
            bf16x8 bv[4];
#pragma unroll
            for (int g = 0; g < 4; g++)
                bv[g] = *(const bf16x8*)(Bg[g] + kk * 512);
            bf16x8 a[2];
#pragma unroll
            for (int mi = 0; mi < 2; mi++)
                a[mi] = *(const bf16x8*)&sA[(mi * 16 + r16) * 1024
                                            + (((kk * 4 + quad) ^ key) * 8)];
#pragma unroll
            for (int g = 0; g < 4; g++)
#pragma unroll
                for (int mi = 0; mi < 2; mi++)
                    acc[g][mi] = mfma16(a[mi], bv[g], acc[g][mi]);
        }
        int u = n0 + w * 16 + r16;
        const float* vx = VX + (size_t)t * 4096;
        float v0 = vx[u], v1 = vx[1024 + u], v2 = vx[2048 + u], v3 = vx[3072 + u];
#pragma unroll
        for (int mi = 0; mi < 2; mi++)
#pragma unroll
            for (int r = 0; r < 4; r++) {
                int m = m0 + mi * 16 + quad * 4 + r;
                float gi = acc[0][mi][r] + v0;
                float gf = acc[1][mi][r] + v1;
                float gg = acc[2][mi][r] + v2;
                float go = acc[3][mi][r] + v3;
                size_t cix = (size_t)m * 1024 + u;
                float cn = sigm(gf) * c_st[cix] + sigm(gi) * tanh_f(gg);
                c_st[cix] = cn;
                h_out[cix] = __float2bfloat16(sigm(go) * tanh_f(cn));
            }
    } else {
        const __hip_bfloat16* Bq = WattnP
            + ((size_t)((b2 & 15) * 4 + w) * 128 + quad) * 128 + r16 * 8;
        f32x4 acc[2] = {};
#pragma unroll 4
        for (int kk = 0; kk < 32; kk++) {
            bf16x8 bv = *(const bf16x8*)(Bq + kk * 512);
            bf16x8 a[2];
#pragma unroll
            for (int mi = 0; mi < 2; mi++)
                a[mi] = *(const bf16x8*)&sA[(mi * 16 + r16) * 1024
                                            + (((kk * 4 + quad) ^ key) * 8)];
#pragma unroll
            for (int mi = 0; mi < 2; mi++)
                acc[mi] = mfma16(a[mi], bv, acc[mi]);
        }
        int n = n0 + w * 16 + r16;
#pragma unroll
        for (int mi = 0; mi < 2; mi++)
#pragma unroll
            for (int r = 0; r < 4; r++) {
                int m = m0 + mi * 16 + quad * 4 + r;
                qout[(size_t)m * 1024 + n] = acc[mi][r];
            }
    }
}

// ======== MFMA attention: block = b, all 32 t batched ========================
__global__ __launch_bounds__(512, 2) void kattn_mfma(
    const float* __restrict__ qall,           // [32][256][1024]
    const unsigned char* __restrict__ ctx8,   // [64][1024][1024] fp8 (x16)
    const unsigned char* __restrict__ ctxT8,  // [1024][1024][64] fp8 (x16)
    const __hip_bfloat16* __restrict__ hAll,  // [33][256][1024]
    const __hip_bfloat16* __restrict__ WcT,   // [64][2048]
    const float* __restrict__ bcomp,          // [64]
    const int* __restrict__ actions,          // [256][32]
    float* __restrict__ nllT)                 // [32][256]
{
    __shared__ __align__(16) unsigned char sQ8[32 * 1032];   // q fp8 (/4), row stride 1032
    __shared__ float sS[4][32][65];                          // scores
    __shared__ __align__(16) unsigned char sP[4 * 32 * 72];  // P fp8 (x16/S), stride 72
    __shared__ __align__(16) ushort_t sPool[32 * 1032];      // pooled ctx bf16, stride 1032
    __shared__ float slg[32 * 68];                           // logits

    int b = blockIdx.x;
    int tid = threadIdx.x;
    int lane = tid & 63, w = tid >> 6;
    int r16 = lane & 15, quad = lane >> 4;
    const size_t LSTR = 1024 * 1024;

    // ---- phase Q: qall fp32 -> fp8 (x 1/4) into LDS
    for (int i = 0; i < 64; i++) {
        int idx = i * 512 + tid;           // coalesced over tid
        int t = idx >> 10, e = idx & 1023;
        float v = qall[((size_t)t * 256 + b) * 1024 + e] * 0.25f;
        sQ8[t * 1032 + e] = f32_to_fp8(v);
    }
    __syncthreads();

    // ---- GEMM1: wave w -> (n = w>>1, l-half lh = w&1)
    {
        int n = w >> 1, lh = w & 1;
        int l0 = lh * 32;
        f32x4 c[2][2] = {};
        const unsigned char* cbase = ctx8 + (size_t)(b * 4 + n) * 1024;
        for (int k0 = 0; k0 < 1024; k0 += 32) {
            long a[2], bv[2];
#pragma unroll
            for (int mt = 0; mt < 2; mt++)
                __builtin_memcpy(&a[mt], &sQ8[(mt * 16 + r16) * 1032 + k0 + quad * 8], 8);
#pragma unroll
            for (int lt = 0; lt < 2; lt++)
                bv[lt] = *(const long*)(cbase + (size_t)(l0 + lt * 16 + r16) * LSTR
                                        + k0 + quad * 8);
#pragma unroll
            for (int mt = 0; mt < 2; mt++)
#pragma unroll
                for (int lt = 0; lt < 2; lt++)
                    c[mt][lt] = mfma8(a[mt], bv[lt], c[mt][lt]);
        }
#pragma unroll
        for (int mt = 0; mt < 2; mt++)
#pragma unroll
            for (int lt = 0; lt < 2; lt++)
#pragma unroll
                for (int r = 0; r < 4; r++)
                    sS[n][mt * 16 + quad * 4 + r][l0 + lt * 16 + r16] = c[mt][lt][r];
    }
    __syncthreads();

    // ---- softmax over l, P = fp8(16 * p / S). s = D/4 (q was /4, ctx x16).
    if (tid < 128) {
        int n = tid >> 5, t = tid & 31;
        const float* row = &sS[n][t][0];
        float sum = 0.f;
        for (int l = 0; l < 64; l++)
            sum += __expf(fminf(row[l] * 0.25f, 60.f));
        float inv = 16.0f / sum;
        unsigned char* pr = &sP[(n * 32 + t) * 72];
        for (int l = 0; l < 64; l++)
            pr[l] = f32_to_fp8(__expf(fminf(row[l] * 0.25f, 60.f)) * inv);
    }
    __syncthreads();

    // ---- GEMM2: wave w -> e-range [w*128, w*128+128), loop n, pool in regs
    {
        int e0 = w * 128;
        f32x4 pool[2][8];
#pragma unroll
        for (int mt = 0; mt < 2; mt++)
#pragma unroll
            for (int et = 0; et < 8; et++)
#pragma unroll
                for (int r = 0; r < 4; r++) pool[mt][et][r] = -3.4e38f;

        for (int n = 0; n < 4; n++) {
            f32x4 c[2][8] = {};
            const unsigned char* tbase = ctxT8 + (size_t)(b * 4 + n) * 1024 * 64;
#pragma unroll
            for (int k0 = 0; k0 < 64; k0 += 32) {
                long a[2];
#pragma unroll
                for (int mt = 0; mt < 2; mt++)
                    __builtin_memcpy(&a[mt], &sP[(n * 32 + mt * 16 + r16) * 72 + k0 + quad * 8], 8);
#pragma unroll
                for (int et = 0; et < 8; et++) {
                    long bv = *(const long*)(tbase + (size_t)(e0 + et * 16 + r16) * 64
                                             + k0 + quad * 8);
#pragma unroll
                    for (int mt = 0; mt < 2; mt++)
                        c[mt][et] = mfma8(a[mt], bv, c[mt][et]);
                }
            }
#pragma unroll
            for (int mt = 0; mt < 2; mt++)
#pragma unroll
                for (int et = 0; et < 8; et++)
#pragma unroll
                    for (int r = 0; r < 4; r++)
                        pool[mt][et][r] = fmaxf(pool[mt][et][r], c[mt][et][r] * (1.0f / 256.0f));
        }
#pragma unroll
        for (int mt = 0; mt < 2; mt++)
#pragma unroll
            for (int et = 0; et < 8; et++)
#pragma unroll
                for (int r = 0; r < 4; r++) {
                    int t = mt * 16 + quad * 4 + r;
                    int e = e0 + et * 16 + r16;
                    __hip_bfloat16 hb = __float2bfloat16(pool[mt][et][r]);
                    sPool[t * 1032 + e] = *(ushort_t*)&hb;
                }
    }
    __syncthreads();

    // ---- GEMM3 logits: wave w -> (mt = w&1, pt = w>>1)
    {
        int mt = w & 1, pt = w >> 1;
        f32x4 c = {};
        const __hip_bfloat16* hrow = hAll + ((size_t)(mt * 16 + r16) * 256 + b) * 1024;
        const __hip_bfloat16* wrow = WcT + (size_t)(pt * 16 + r16) * 2048;
        for (int k0 = 0; k0 < 2048; k0 += 32) {
            bf16x8 a;
            if (k0 < 1024)
                a = *(const bf16x8*)(hrow + k0 + quad * 8);
            else
                a = *(const bf16x8*)&sPool[(mt * 16 + r16) * 1032 + (k0 - 1024) + quad * 8];
            bf16x8 bv = *(const bf16x8*)(wrow + k0 + quad * 8);
            c = mfma16(a, bv, c);
        }
#pragma unroll
        for (int r = 0; r < 4; r++) {
            int t = mt * 16 + quad * 4 + r;
            int p = pt * 16 + r16;
            slg[t * 68 + p] = c[r] + bcomp[p];
        }
    }
    __syncthreads();

    // ---- NLL per t
    if (tid < 32) {
        int t = tid;
        const float* row = &slg[t * 68];
        float m = -3.4e38f;
        for (int p = 0; p < 64; p++) m = fmaxf(m, row[p]);
        float se = 0.f;
        for (int p = 0; p < 64; p++) se += __expf(row[p] - m);
        int a = actions[b * 32 + t];
        nllT[t * 256 + b] = m + __logf(se) - row[a];
    }
}

// ---------------- decoder init: max-pool final states over io examples -------
__global__ __launch_bounds__(256) void kinit_dec(
    const __hip_bfloat16* __restrict__ hf,  // final h (buf0): [2][1024][512]
    const float* __restrict__ cf,
    __hip_bfloat16* __restrict__ h0,        // [256][1024] (hAll[0])
    float* __restrict__ c0)
{
    int idx = blockIdx.x * 256 + threadIdx.x;
    int b = idx >> 10, e = idx & 1023;
    int dir = e >> 9, u = e & 511;
    const __hip_bfloat16* hs = hf + (size_t)dir * 1024 * 512;
    const float* cs = cf + (size_t)dir * 1024 * 512;
    float hv = -3.4e38f, cv = -3.4e38f;
#pragma unroll
    for (int n = 0; n < 4; n++) {
        size_t ix = (size_t)(b * 4 + n) * 512 + u;
        hv = fmaxf(hv, __bfloat162float(hs[ix]));
        cv = fmaxf(cv, cs[ix]);
    }
    h0[idx] = __float2bfloat16(hv);
    c0[idx] = cv;
}

__global__ void kfinal(const float* __restrict__ nllT, void* __restrict__ out,
                       const int* __restrict__ mode) {
    int i = threadIdx.x;
    float s = 0.f;
#pragma unroll
    for (int t = 0; t < 32; t++) s += nllT[t * 256 + i];
    if (*mode) ((__hip_bfloat16*)out)[i] = __float2bfloat16(s);
    else       ((float*)out)[i] = s;
}

// -----------------------------------------------------------------------------
extern "C" void kernel_launch(void* const* d_in, const int* in_sizes, int n_in,
                              void* d_out, int out_size, void* d_ws, size_t ws_size,
                              hipStream_t stream) {
    const int* exs = (const int*)d_in[0];
    const int* cls = (const int*)d_in[1];
    const void* E_raw     = d_in[2];
    const void* WiF_raw   = d_in[3];
    const void* WhF_raw   = d_in[4];
    const void* bF_raw    = d_in[5];
    const void* WiB_raw   = d_in[6];
    const void* WhB_raw   = d_in[7];
    const void* bB_raw    = d_in[8];
    const void* Wattn_raw = d_in[9];
    const void* Wcomp_raw = d_in[10];
    const void* bcomp_raw = d_in[11];
    const void* vWi_raw   = d_in[12];
    const void* vWh_raw   = d_in[13];
    const void* vb_raw    = d_in[14];
    const void* fe_raw    = d_in[15];
    const int* actions = (const int*)d_in[16];
    (void)in_sizes; (void)n_in; (void)out_size; (void)ws_size;

    char* w = (char*)d_ws;
    size_t off = 0;
    auto take = [&](size_t bytes) -> char* {
        char* p = w + off;
        off = (off + bytes + 255) & ~(size_t)255;
        return p;
    };
    __hip_bfloat16* WhT    = (__hip_bfloat16*)take(2ull * 2048 * 512 * 2);
    __hip_bfloat16* WiT    = (__hip_bfloat16*)take(2ull * 2048 * 256 * 2);
    __hip_bfloat16* vWhT   = (__hip_bfloat16*)take(4096ull * 1024 * 2);
    __hip_bfloat16* vWiT   = (__hip_bfloat16*)take(4096ull * 1024 * 2);
    __hip_bfloat16* WattnT = (__hip_bfloat16*)take(1024ull * 1024 * 2);
    __hip_bfloat16* WcT    = (__hip_bfloat16*)take(64ull * 2048 * 2);
    __hip_bfloat16* Ebf    = (__hip_bfloat16*)take(128ull * 128 * 2);
    __hip_bfloat16* febf   = (__hip_bfloat16*)take(32ull * 1024 * 2);
    __hip_bfloat16* WhP    = (__hip_bfloat16*)take(2ull * 2048 * 512 * 2);   // packed
    __hip_bfloat16* vWhP   = (__hip_bfloat16*)take(4096ull * 1024 * 2);      // packed
    __hip_bfloat16* WattnP = (__hip_bfloat16*)take(1024ull * 1024 * 2);      // packed
    float* bFf   = (float*)take(2048 * 4);
    float* bBf   = (float*)take(2048 * 4);
    float* bcf   = (float*)take(64 * 4);
    float* vbf   = (float*)take(4096 * 4);
    float* Gtab  = (float*)take(4ull * 128 * 2048 * 4);
    float* VX    = (float*)take(32ull * 4096 * 4);
    __hip_bfloat16* hEnc = (__hip_bfloat16*)take(2ull * 2 * 1024 * 512 * 2); // [buf][dir][1024][512]
    float* cEnc = (float*)take(2ull * 1024 * 512 * 4);
    __hip_bfloat16* hAll = (__hip_bfloat16*)take(33ull * 256 * 1024 * 2);    // h_0..h_32
    float* cDec = (float*)take(256ull * 1024 * 4);
    float* qall = (float*)take(32ull * 256 * 1024 * 4);
    float* nllT = (float*)take(32ull * 256 * 4);
    int*   mode = (int*)take(256);
    unsigned char* ctx8  = (unsigned char*)take(64ull * 1024 * 1024);  // fp8 [l][b4n][e]
    unsigned char* ctxT8 = (unsigned char*)take(64ull * 1024 * 1024);  // fp8 [b4n][e][l]

    (void)hipMemsetAsync(hEnc, 0, 2ull * 1024 * 512 * 2, stream);  // h buf0, both dirs
    (void)hipMemsetAsync(cEnc, 0, 2ull * 1024 * 512 * 4, stream);

    kdetect<<<1, 128, 0, stream>>>((const unsigned int*)E_raw, mode);

    kcvt_bf16<<<64, 256, 0, stream>>>(E_raw,  Ebf,  128 * 128, mode);
    kcvt_bf16<<<128, 256, 0, stream>>>(fe_raw, febf, 32 * 1024, mode);
    kcvt_f32<<<8, 256, 0, stream>>>(bF_raw, bFf, 2048, mode);
    kcvt_f32<<<8, 256, 0, stream>>>(bB_raw, bBf, 2048, mode);
    kcvt_f32<<<1, 256, 0, stream>>>(bcomp_raw, bcf, 64, mode);
    kcvt_f32<<<16, 256, 0, stream>>>(vb_raw, vbf, 4096, mode);

    ktranspose_cvt<<<dim3(32, 8),  256, 0, stream>>>(WhF_raw,   WhT,              512, 2048, mode);
    ktranspose_cvt<<<dim3(32, 8),  256, 0, stream>>>(WhB_raw,   WhT + 2048 * 512, 512, 2048, mode);
    ktranspose_cvt<<<dim3(32, 4),  256, 0, stream>>>(WiF_raw,   WiT,              256, 2048, mode);
    ktranspose_cvt<<<dim3(32, 4),  256, 0, stream>>>(WiB_raw,   WiT + 2048 * 256, 256, 2048, mode);
    ktranspose_cvt<<<dim3(64, 16), 256, 0, stream>>>(vWh_raw,   vWhT,            1024, 4096, mode);
    ktranspose_cvt<<<dim3(64, 16), 256, 0, stream>>>(vWi_raw,   vWiT,            1024, 4096, mode);
    ktranspose_cvt<<<dim3(16, 16), 256, 0, stream>>>(Wattn_raw, WattnT,          1024, 1024, mode);
    ktranspose_cvt<<<dim3(1, 32),  256, 0, stream>>>(Wcomp_raw, WcT,             2048, 64,   mode);

    // fragment-order packing for B-direct GEMMs
    kpack_frag<<<1024, 256, 0, stream>>>(WhT,    WhP,    4096, 512);
    kpack_frag<<<2048, 256, 0, stream>>>(vWhT,   vWhP,   4096, 1024);
    kpack_frag<<<512,  256, 0, stream>>>(WattnT, WattnP, 1024, 1024);

    kprep_gtab<<<256, 256, 0, stream>>>(Ebf, WiT, bFf, bBf, Gtab);
    kprep_vx<<<32, 256, 0, stream>>>(febf, vWiT, vbf, VX);

    const size_t HB = 2ull * 1024 * 512;
    for (int t = 0; t < 64; t++) {
        kenc_step<<<256, 512, 0, stream>>>(t, WhP, Gtab, exs, cls,
                                           hEnc + (size_t)(t & 1) * HB,
                                           hEnc + (size_t)((t + 1) & 1) * HB,
                                           cEnc, ctx8);
    }
    ktrans8<<<dim3(1024, 16), 256, 0, stream>>>(ctx8, ctxT8);
    kinit_dec<<<1024, 256, 0, stream>>>(hEnc, cEnc, hAll, cDec);

    const size_t HD = 256ull * 1024;
    for (int t = 0; t < 32; t++) {
        kdec_gemm<<<256, 256, 0, stream>>>(t, vWhP, WattnP, VX,
                                           hAll + (size_t)t * HD,
                                           hAll + (size_t)(t + 1) * HD,
                                           cDec, qall + (size_t)t * HD);
    }
    kattn_mfma<<<256, 512, 0, stream>>>(qall, ctx8, ctxT8, hAll, WcT, bcf,
                                        actions, nllT);
    kfinal<<<1, 256, 0, stream>>>(nllT, d_out, mode);
}

// Round 5
// 1708.347 us; speedup vs baseline: 1.0902x; 1.0902x over previous
//
#include <hip/hip_runtime.h>
#include <hip/hip_bf16.h>

typedef __bf16 bf16x8 __attribute__((ext_vector_type(8)));
typedef float  f32x4  __attribute__((ext_vector_type(4)));
typedef float  f32x2  __attribute__((ext_vector_type(2)));
typedef unsigned int u32x4 __attribute__((ext_vector_type(4)));
typedef unsigned short ushort_t;
static_assert(sizeof(bf16x8) == 16, "bf16x8 must be 16B");

#define DEV __device__ __forceinline__

DEV f32x4 mfma16(bf16x8 a, bf16x8 b, f32x4 c) {
    return __builtin_amdgcn_mfma_f32_16x16x32_bf16(a, b, c, 0, 0, 0);
}
DEV f32x4 mfma8(long a, long b, f32x4 c) {
    return __builtin_amdgcn_mfma_f32_16x16x32_fp8_fp8(a, b, c, 0, 0, 0);
}
DEV float sigm(float x)   { return 1.0f / (1.0f + __expf(-x)); }
DEV float tanh_f(float x) { return 2.0f / (1.0f + __expf(-2.0f * x)) - 1.0f; }

// async global->LDS, 16B per lane; lds dest must be wave-uniform base (+lane*16)
DEV void glds16(const __hip_bfloat16* g, __hip_bfloat16* l) {
    __builtin_amdgcn_global_load_lds(
        (const __attribute__((address_space(1))) unsigned int*)g,
        (__attribute__((address_space(3))) unsigned int*)l, 16, 0, 0);
}

DEV unsigned char f32_to_fp8(float v) {
    int p = __builtin_amdgcn_cvt_pk_fp8_f32(v, v, 0, false);
    return (unsigned char)(p & 0xFF);
}

// ---------------- dtype detection: 1 = inputs are bf16, 0 = inputs are fp32 --
__global__ __launch_bounds__(128) void kdetect(const unsigned int* __restrict__ raw,
                                               int* __restrict__ mode) {
    __shared__ int cnt;
    if (threadIdx.x == 0) cnt = 0;
    __syncthreads();
    unsigned int w = raw[threadIdx.x];
    unsigned short lo = (unsigned short)(w & 0xFFFFu);
    unsigned int f32bits = ((unsigned int)lo) << 16;
    float v;
    __builtin_memcpy(&v, &f32bits, 4);
    float a = fabsf(v);
    if (a >= 1e-4f && a <= 1.0f) atomicAdd(&cnt, 1);
    __syncthreads();
    if (threadIdx.x == 0) *mode = (cnt >= 64) ? 1 : 0;
}

__global__ __launch_bounds__(256) void kcvt_bf16(const void* __restrict__ src,
                                                 __hip_bfloat16* __restrict__ dst,
                                                 int n, const int* __restrict__ mode) {
    int i = blockIdx.x * 256 + threadIdx.x;
    if (i >= n) return;
    if (*mode) dst[i] = ((const __hip_bfloat16*)src)[i];
    else       dst[i] = __float2bfloat16(((const float*)src)[i]);
}

__global__ __launch_bounds__(256) void kcvt_f32(const void* __restrict__ src,
                                                float* __restrict__ dst,
                                                int n, const int* __restrict__ mode) {
    int i = blockIdx.x * 256 + threadIdx.x;
    if (i >= n) return;
    if (*mode) dst[i] = __bfloat162float(((const __hip_bfloat16*)src)[i]);
    else       dst[i] = ((const float*)src)[i];
}

// --------- tiled transpose + convert: out_bf16[c][r] = (bf16)in[r][c] --------
__global__ __launch_bounds__(256) void ktranspose_cvt(const void* __restrict__ src,
                                                      __hip_bfloat16* __restrict__ out,
                                                      int R, int C,
                                                      const int* __restrict__ mode) {
    __shared__ float tile[64][65];
    int c0 = blockIdx.x * 64, r0 = blockIdx.y * 64;
    int tx = threadIdx.x & 63, ty = threadIdx.x >> 6;
    int m = *mode;
#pragma unroll
    for (int i = ty; i < 64; i += 4) {
        size_t ix = (size_t)(r0 + i) * C + (c0 + tx);
        tile[i][tx] = m ? __bfloat162float(((const __hip_bfloat16*)src)[ix])
                        : ((const float*)src)[ix];
    }
    __syncthreads();
#pragma unroll
    for (int i = ty; i < 64; i += 4)
        out[(size_t)(c0 + i) * R + (r0 + tx)] = __float2bfloat16(tile[tx][i]);
}

// ------ prep: G tables, gate-interleaved: G[dh][v][u<512][g<4] = E@Wi (+b) ---
__global__ __launch_bounds__(256) void kprep_gtab(
    const __hip_bfloat16* __restrict__ E,    // [128][128]
    const __hip_bfloat16* __restrict__ WiT,  // [2][2048][256]
    const float* __restrict__ bF,
    const float* __restrict__ bB,
    float* __restrict__ G)                   // [4][128][512][4]
{
    int dh = blockIdx.x >> 6;
    int dir = dh >> 1, half = dh & 1;
    int m0 = ((blockIdx.x >> 5) & 1) * 64;
    int n0 = (blockIdx.x & 31) * 64;
    int lane = threadIdx.x & 63, wid = threadIdx.x >> 6;
    int wrow = wid >> 1, wcol = wid & 1;
    int r16 = lane & 15, quad = lane >> 4;

    f32x4 acc[2][2] = {};
    const __hip_bfloat16* Ap = E + (size_t)(m0 + wrow * 32 + r16) * 128 + quad * 8;
    const __hip_bfloat16* Bp = WiT + (size_t)dir * 2048 * 256
                             + (size_t)(n0 + wcol * 32 + r16) * 256 + half * 128 + quad * 8;
#pragma unroll
    for (int kb = 0; kb < 128; kb += 32) {
        bf16x8 a0 = *(const bf16x8*)(Ap + kb);
        bf16x8 a1 = *(const bf16x8*)(Ap + 16 * 128 + kb);
        bf16x8 b0 = *(const bf16x8*)(Bp + kb);
        bf16x8 b1 = *(const bf16x8*)(Bp + 16 * 256 + kb);
        acc[0][0] = mfma16(a0, b0, acc[0][0]);
        acc[0][1] = mfma16(a0, b1, acc[0][1]);
        acc[1][0] = mfma16(a1, b0, acc[1][0]);
        acc[1][1] = mfma16(a1, b1, acc[1][1]);
    }
    const float* bias = dir ? bB : bF;
    float* Gt = G + (size_t)dh * 128 * 2048;
#pragma unroll
    for (int rt = 0; rt < 2; rt++)
#pragma unroll
        for (int ct = 0; ct < 2; ct++)
#pragma unroll
            for (int r = 0; r < 4; r++) {
                int mm = m0 + wrow * 32 + rt * 16 + quad * 4 + r;
                int j = n0 + wcol * 32 + ct * 16 + r16;
                float v = acc[rt][ct][r];
                if (half == 0) v += bias[j];
                int g = j >> 9, u = j & 511;
                Gt[((size_t)mm * 512 + u) * 4 + g] = v;
            }
}

// ---------------- prep: VX[t][j] = field_emb @ v_Wi + v_b --------------------
__global__ __launch_bounds__(256) void kprep_vx(
    const __hip_bfloat16* __restrict__ fe,    // [32][1024]
    const __hip_bfloat16* __restrict__ vWiT,  // [4096][1024]
    const float* __restrict__ vb,             // [4096]
    float* __restrict__ VX)                   // [32][4096]
{
    int n0 = blockIdx.x * 128;
    int lane = threadIdx.x & 63, wid = threadIdx.x >> 6;
    int r16 = lane & 15, quad = lane >> 4;
    f32x4 acc[2][2] = {};
    const __hip_bfloat16* Ap = fe + (size_t)r16 * 1024 + quad * 8;
    const __hip_bfloat16* Bp = vWiT + (size_t)(n0 + wid * 32 + r16) * 1024 + quad * 8;
    for (int kb = 0; kb < 1024; kb += 32) {
        bf16x8 a0 = *(const bf16x8*)(Ap + kb);
        bf16x8 a1 = *(const bf16x8*)(Ap + 16 * 1024 + kb);
        bf16x8 b0 = *(const bf16x8*)(Bp + kb);
        bf16x8 b1 = *(const bf16x8*)(Bp + 16 * 1024 + kb);
        acc[0][0] = mfma16(a0, b0, acc[0][0]);
        acc[0][1] = mfma16(a0, b1, acc[0][1]);
        acc[1][0] = mfma16(a1, b0, acc[1][0]);
        acc[1][1] = mfma16(a1, b1, acc[1][1]);
    }
#pragma unroll
    for (int rt = 0; rt < 2; rt++)
#pragma unroll
        for (int ct = 0; ct < 2; ct++)
#pragma unroll
            for (int r = 0; r < 4; r++) {
                int m = rt * 16 + quad * 4 + r;
                int j = n0 + wid * 32 + ct * 16 + r16;
                VX[(size_t)m * 4096 + j] = acc[rt][ct][r] + vb[j];
            }
}

// ======== encoder LSTM step: 512 blocks (dir x 16 mt x 16 us), 64m x 32u =====
// Re-tiled from 32m x 64u: LDS 72KB -> 48KB (3 blocks/CU), B L2 traffic halved
// (each block reads 128 B-rows instead of 256 for a 2x-larger m-tile).
// Same verified inner structure: glds16 double-buffer + chunk-XOR swizzle.
__global__ __launch_bounds__(256, 3) void kenc_step(
    int t,
    const __hip_bfloat16* __restrict__ WhT,   // [2][2048][512]
    const float* __restrict__ Gtab,           // [4][128][512][4]
    const int* __restrict__ exs,
    const int* __restrict__ cls,
    const __hip_bfloat16* __restrict__ h_in,  // [2][1024][512]
    __hip_bfloat16* __restrict__ h_out,
    float* __restrict__ c_st,                 // [2][1024][512]
    unsigned char* __restrict__ ctx8)         // [64][256][4][1024] fp8 (x16)
{
    __shared__ __align__(16) __hip_bfloat16 sA[2][64 * 64];   // 2 x 8KB
    __shared__ __align__(16) __hip_bfloat16 sB[2][128 * 64];  // 2 x 16KB

    int bid = blockIdx.x;
    int dir = bid >> 8;
    int mt  = (bid >> 4) & 15;
    int us  = bid & 15;
    int l = dir ? (63 - t) : t;
    int m0 = mt * 64, u0 = us * 32;

    int lane = threadIdx.x & 63, w = threadIdx.x >> 6;   // 4 waves
    int wm = w >> 1, wu = w & 1;                          // 2m x 2u
    int r16 = lane & 15, quad = lane >> 4;
    int srow = lane >> 3;
    int scol = ((lane & 7) ^ srow) * 8;   // swizzled global source column

    const __hip_bfloat16* Ab = h_in + (size_t)dir * 1024 * 512;
    const __hip_bfloat16* Bb = WhT + (size_t)dir * 2048 * 512;

    f32x4 acc[4][2] = {};  // [gate][mi]

    auto stage = [&](int buf, int it) {
        int kb = it * 64;
        // A: 64 rows, 8 calls total -> 2 per wave
#pragma unroll
        for (int c = 0; c < 2; c++) {
            int r8 = (w * 2 + c) * 8;
            glds16(Ab + (size_t)(m0 + r8 + srow) * 512 + kb + scol,
                   &sA[buf][r8 * 64]);
        }
        // B: 128 rows (4 gates x 32 u), 16 calls -> 4 per wave
#pragma unroll
        for (int c = 0; c < 4; c++) {
            int rl = (w * 4 + c) * 8;
            int rr = rl + srow;
            int g = rr >> 5, j = rr & 31;
            glds16(Bb + (size_t)(g * 512 + u0 + j) * 512 + kb + scol,
                   &sB[buf][rl * 64]);
        }
    };

    stage(0, 0);
    __syncthreads();
    int buf = 0;
    const int NIT = 8;  // 512/64
    const int sw = r16 & 7;
    for (int it = 0; it < NIT; it++) {
        if (it + 1 < NIT) stage(buf ^ 1, it + 1);
#pragma unroll
        for (int k32 = 0; k32 < 64; k32 += 32) {
            int co = (((k32 >> 3) + quad) ^ sw) * 8;   // swizzled ds_read column
            bf16x8 a[2], bf[4];
#pragma unroll
            for (int mi = 0; mi < 2; mi++)
                a[mi] = *(const bf16x8*)&sA[buf][(wm * 32 + mi * 16 + r16) * 64 + co];
#pragma unroll
            for (int g = 0; g < 4; g++)
                bf[g] = *(const bf16x8*)&sB[buf][(g * 32 + wu * 16 + r16) * 64 + co];
#pragma unroll
            for (int g = 0; g < 4; g++)
#pragma unroll
                for (int mi = 0; mi < 2; mi++)
                    acc[g][mi] = mfma16(a[mi], bf[g], acc[g][mi]);
        }
        __syncthreads();
        buf ^= 1;
    }

    // epilogue: thread owns u = u0 + wu*16 + r16, 8 m's
    int u = u0 + wu * 16 + r16;
    size_t cbase = (size_t)dir * 1024 * 512;
    const float* GeT = Gtab + (size_t)(dir * 2) * 128 * 2048;
    const float* GcT = GeT + 128 * 2048;
#pragma unroll
    for (int mi = 0; mi < 2; mi++)
#pragma unroll
        for (int r = 0; r < 4; r++) {
            int m = m0 + wm * 32 + mi * 16 + quad * 4 + r;
            int vE = exs[l * 1024 + m], vC = cls[l * 1024 + m];
            f32x4 ge = *(const f32x4*)&GeT[((size_t)vE * 512 + u) * 4];
            f32x4 gc = *(const f32x4*)&GcT[((size_t)vC * 512 + u) * 4];
            float gi = acc[0][mi][r] + ge[0] + gc[0];
            float gf = acc[1][mi][r] + ge[1] + gc[1];
            float gg = acc[2][mi][r] + ge[2] + gc[2];
            float go = acc[3][mi][r] + ge[3] + gc[3];
            size_t cix = cbase + (size_t)m * 512 + u;
            float cn = sigm(gf) * c_st[cix] + sigm(gi) * tanh_f(gg);
            c_st[cix] = cn;
            float hn = sigm(go) * tanh_f(cn);
            h_out[cix] = __float2bfloat16(hn);
            ctx8[(((size_t)l * 256 + (m >> 2)) * 4 + (m & 3)) * 1024 + dir * 512 + u]
                = f32_to_fp8(hn * 16.0f);
        }
}

// ---- fp8 ctx transpose: ctxT8[b4n][e][l] = ctx8[l][b4n][e] ------------------
__global__ __launch_bounds__(256) void ktrans8(const unsigned char* __restrict__ ctx8,
                                               unsigned char* __restrict__ ctxT8) {
    __shared__ unsigned int tile[64][17];   // 64 l-rows x 64 e-bytes (16 u32 + pad)
    int b4n = blockIdx.x;                   // 0..1023
    int e0 = blockIdx.y * 64;               // e-tile
    int tid = threadIdx.x;
#pragma unroll
    for (int pass = 0; pass < 4; pass++) {
        int idx = pass * 256 + tid;
        int l = idx >> 4, c = idx & 15;
        tile[l][c] = *(const unsigned int*)(ctx8 + (size_t)l * (1024 * 1024)
                                            + (size_t)b4n * 1024 + e0 + c * 4);
    }
    __syncthreads();
    const unsigned char* tb = (const unsigned char*)tile;
#pragma unroll
    for (int pass = 0; pass < 4; pass++) {
        int idx = pass * 256 + tid;
        int e = idx >> 4, c = idx & 15;
        unsigned int v = 0;
#pragma unroll
        for (int j = 0; j < 4; j++) {
            unsigned int byte = tb[(size_t)(c * 4 + j) * 68 + e];
            v |= byte << (8 * j);
        }
        *(unsigned int*)(ctxT8 + ((size_t)b4n * 1024 + e0 + e) * 64 + c * 4) = v;
    }
}

// ======== decoder fused GEMM: cell (0..127: 32m x 64u) + q (128..255) ========
__global__ __launch_bounds__(256, 2) void kdec_gemm(
    int t,
    const __hip_bfloat16* __restrict__ vWhT,   // [4096][1024]
    const __hip_bfloat16* __restrict__ WattnT, // [1024][1024]
    const float* __restrict__ VX,              // [32][4096]
    const __hip_bfloat16* __restrict__ h_in,   // [256][1024]  (h_t = hAll[t])
    __hip_bfloat16* __restrict__ h_out,        // [256][1024]  (hAll[t+1])
    float* __restrict__ c_st,                  // [256][1024]
    float* __restrict__ qout)                  // [256][1024]  (qall[t])
{
    __shared__ __align__(16) __hip_bfloat16 sA[2][32 * 64];
    __shared__ __align__(16) __hip_bfloat16 sB[2][256 * 64];

    int bid = blockIdx.x;
    int lane = threadIdx.x & 63, w = threadIdx.x >> 6;
    int r16 = lane & 15, quad = lane >> 4;
    int srow = lane >> 3;
    int scol = ((lane & 7) ^ srow) * 8;   // swizzled global source column
    const int NIT = 16;  // 1024/64
    const int sw = r16 & 7;

    if (bid < 128) {
        int m0 = (bid >> 4) * 32, u0 = (bid & 15) * 64;
        f32x4 acc[4][2] = {};
        auto stage = [&](int buf, int it) {
            int kb = it * 64;
            glds16(h_in + (size_t)(m0 + w * 8 + srow) * 1024 + kb + scol,
                   &sA[buf][(w * 8) * 64]);
#pragma unroll
            for (int c = 0; c < 8; c++) {
                int rl = w * 64 + c * 8;
                int rr = rl + srow;
                int g = rr >> 6, j = rr & 63;
                glds16(vWhT + (size_t)(g * 1024 + u0 + j) * 1024 + kb + scol,
                       &sB[buf][rl * 64]);
            }
        };
        stage(0, 0);
        __syncthreads();
        int buf = 0;
        for (int it = 0; it < NIT; it++) {
            if (it + 1 < NIT) stage(buf ^ 1, it + 1);
#pragma unroll
            for (int k32 = 0; k32 < 64; k32 += 32) {
                int co = (((k32 >> 3) + quad) ^ sw) * 8;
                bf16x8 a[2], bf[4];
#pragma unroll
                for (int mi = 0; mi < 2; mi++)
                    a[mi] = *(const bf16x8*)&sA[buf][(mi * 16 + r16) * 64 + co];
#pragma unroll
                for (int g = 0; g < 4; g++)
                    bf[g] = *(const bf16x8*)&sB[buf][(g * 64 + w * 16 + r16) * 64 + co];
#pragma unroll
                for (int g = 0; g < 4; g++)
#pragma unroll
                    for (int mi = 0; mi < 2; mi++)
                        acc[g][mi] = mfma16(a[mi], bf[g], acc[g][mi]);
            }
            __syncthreads();
            buf ^= 1;
        }
        int u = u0 + w * 16 + r16;
        const float* vx = VX + (size_t)t * 4096;
        float v0 = vx[u], v1 = vx[1024 + u], v2 = vx[2048 + u], v3 = vx[3072 + u];
#pragma unroll
        for (int mi = 0; mi < 2; mi++)
#pragma unroll
            for (int r = 0; r < 4; r++) {
                int m = m0 + mi * 16 + quad * 4 + r;
                float gi = acc[0][mi][r] + v0;
                float gf = acc[1][mi][r] + v1;
                float gg = acc[2][mi][r] + v2;
                float go = acc[3][mi][r] + v3;
                size_t cix = (size_t)m * 1024 + u;
                float cn = sigm(gf) * c_st[cix] + sigm(gi) * tanh_f(gg);
                c_st[cix] = cn;
                h_out[cix] = __float2bfloat16(sigm(go) * tanh_f(cn));
            }
    } else {
        int b2 = bid - 128;
        int m0 = (b2 >> 4) * 32, n0 = (b2 & 15) * 64;
        f32x4 acc[2] = {};
        auto stage = [&](int buf, int it) {
            int kb = it * 64;
            glds16(h_in + (size_t)(m0 + w * 8 + srow) * 1024 + kb + scol,
                   &sA[buf][(w * 8) * 64]);
#pragma unroll
            for (int c = 0; c < 2; c++) {
                int rl = w * 16 + c * 8;
                glds16(WattnT + (size_t)(n0 + rl + srow) * 1024 + kb + scol,
                       &sB[buf][rl * 64]);
            }
        };
        stage(0, 0);
        __syncthreads();
        int buf = 0;
        for (int it = 0; it < NIT; it++) {
            if (it + 1 < NIT) stage(buf ^ 1, it + 1);
#pragma unroll
            for (int k32 = 0; k32 < 64; k32 += 32) {
                int co = (((k32 >> 3) + quad) ^ sw) * 8;
                bf16x8 a[2];
#pragma unroll
                for (int mi = 0; mi < 2; mi++)
                    a[mi] = *(const bf16x8*)&sA[buf][(mi * 16 + r16) * 64 + co];
                bf16x8 bf = *(const bf16x8*)&sB[buf][(w * 16 + r16) * 64 + co];
#pragma unroll
                for (int mi = 0; mi < 2; mi++)
                    acc[mi] = mfma16(a[mi], bf, acc[mi]);
            }
            __syncthreads();
            buf ^= 1;
        }
        int n = n0 + w * 16 + r16;
#pragma unroll
        for (int mi = 0; mi < 2; mi++)
#pragma unroll
            for (int r = 0; r < 4; r++) {
                int m = m0 + mi * 16 + quad * 4 + r;
                qout[(size_t)m * 1024 + n] = acc[mi][r];
            }
    }
}

// ======== MFMA attention: block = b, all 32 t batched ========================
__global__ __launch_bounds__(512, 2) void kattn_mfma(
    const float* __restrict__ qall,           // [32][256][1024]
    const unsigned char* __restrict__ ctx8,   // [64][1024][1024] fp8 (x16)
    const unsigned char* __restrict__ ctxT8,  // [1024][1024][64] fp8 (x16)
    const __hip_bfloat16* __restrict__ hAll,  // [33][256][1024]
    const __hip_bfloat16* __restrict__ WcT,   // [64][2048]
    const float* __restrict__ bcomp,          // [64]
    const int* __restrict__ actions,          // [256][32]
    float* __restrict__ nllT)                 // [32][256]
{
    __shared__ __align__(16) unsigned char sQ8[32 * 1032];   // q fp8 (/4), row stride 1032
    __shared__ float sS[4][32][65];                          // scores
    __shared__ __align__(16) unsigned char sP[4 * 32 * 72];  // P fp8 (x16/S), stride 72
    __shared__ __align__(16) ushort_t sPool[32 * 1032];      // pooled ctx bf16, stride 1032
    __shared__ float slg[32 * 68];                           // logits

    int b = blockIdx.x;
    int tid = threadIdx.x;
    int lane = tid & 63, w = tid >> 6;
    int r16 = lane & 15, quad = lane >> 4;
    const size_t LSTR = 1024 * 1024;

    // ---- phase Q: qall fp32 -> fp8 (x 1/4) into LDS
    for (int i = 0; i < 64; i++) {
        int idx = i * 512 + tid;           // coalesced over tid
        int t = idx >> 10, e = idx & 1023;
        float v = qall[((size_t)t * 256 + b) * 1024 + e] * 0.25f;
        sQ8[t * 1032 + e] = f32_to_fp8(v);
    }
    __syncthreads();

    // ---- GEMM1: wave w -> (n = w>>1, l-half lh = w&1)
    {
        int n = w >> 1, lh = w & 1;
        int l0 = lh * 32;
        f32x4 c[2][2] = {};
        const unsigned char* cbase = ctx8 + (size_t)(b * 4 + n) * 1024;
        for (int k0 = 0; k0 < 1024; k0 += 32) {
            long a[2], bv[2];
#pragma unroll
            for (int mt = 0; mt < 2; mt++)
                __builtin_memcpy(&a[mt], &sQ8[(mt * 16 + r16) * 1032 + k0 + quad * 8], 8);
#pragma unroll
            for (int lt = 0; lt < 2; lt++)
                bv[lt] = *(const long*)(cbase + (size_t)(l0 + lt * 16 + r16) * LSTR
                                        + k0 + quad * 8);
#pragma unroll
            for (int mt = 0; mt < 2; mt++)
#pragma unroll
                for (int lt = 0; lt < 2; lt++)
                    c[mt][lt] = mfma8(a[mt], bv[lt], c[mt][lt]);
        }
#pragma unroll
        for (int mt = 0; mt < 2; mt++)
#pragma unroll
            for (int lt = 0; lt < 2; lt++)
#pragma unroll
                for (int r = 0; r < 4; r++)
                    sS[n][mt * 16 + quad * 4 + r][l0 + lt * 16 + r16] = c[mt][lt][r];
    }
    __syncthreads();

    // ---- softmax over l, P = fp8(16 * p / S). s = D/4 (q was /4, ctx x16).
    if (tid < 128) {
        int n = tid >> 5, t = tid & 31;
        const float* row = &sS[n][t][0];
        float sum = 0.f;
        for (int l = 0; l < 64; l++)
            sum += __expf(fminf(row[l] * 0.25f, 60.f));
        float inv = 16.0f / sum;
        unsigned char* pr = &sP[(n * 32 + t) * 72];
        for (int l = 0; l < 64; l++)
            pr[l] = f32_to_fp8(__expf(fminf(row[l] * 0.25f, 60.f)) * inv);
    }
    __syncthreads();

    // ---- GEMM2: wave w -> e-range [w*128, w*128+128), loop n, pool in regs
    {
        int e0 = w * 128;
        f32x4 pool[2][8];
#pragma unroll
        for (int mt = 0; mt < 2; mt++)
#pragma unroll
            for (int et = 0; et < 8; et++)
#pragma unroll
                for (int r = 0; r < 4; r++) pool[mt][et][r] = -3.4e38f;

        for (int n = 0; n < 4; n++) {
            f32x4 c[2][8] = {};
            const unsigned char* tbase = ctxT8 + (size_t)(b * 4 + n) * 1024 * 64;
#pragma unroll
            for (int k0 = 0; k0 < 64; k0 += 32) {
                long a[2];
#pragma unroll
                for (int mt = 0; mt < 2; mt++)
                    __builtin_memcpy(&a[mt], &sP[(n * 32 + mt * 16 + r16) * 72 + k0 + quad * 8], 8);
#pragma unroll
                for (int et = 0; et < 8; et++) {
                    long bv = *(const long*)(tbase + (size_t)(e0 + et * 16 + r16) * 64
                                             + k0 + quad * 8);
#pragma unroll
                    for (int mt = 0; mt < 2; mt++)
                        c[mt][et] = mfma8(a[mt], bv, c[mt][et]);
                }
            }
#pragma unroll
            for (int mt = 0; mt < 2; mt++)
#pragma unroll
                for (int et = 0; et < 8; et++)
#pragma unroll
                    for (int r = 0; r < 4; r++)
                        pool[mt][et][r] = fmaxf(pool[mt][et][r], c[mt][et][r] * (1.0f / 256.0f));
        }
#pragma unroll
        for (int mt = 0; mt < 2; mt++)
#pragma unroll
            for (int et = 0; et < 8; et++)
#pragma unroll
                for (int r = 0; r < 4; r++) {
                    int t = mt * 16 + quad * 4 + r;
                    int e = e0 + et * 16 + r16;
                    __hip_bfloat16 hb = __float2bfloat16(pool[mt][et][r]);
                    sPool[t * 1032 + e] = *(ushort_t*)&hb;
                }
    }
    __syncthreads();

    // ---- GEMM3 logits: wave w -> (mt = w&1, pt = w>>1)
    {
        int mt = w & 1, pt = w >> 1;
        f32x4 c = {};
        const __hip_bfloat16* hrow = hAll + ((size_t)(mt * 16 + r16) * 256 + b) * 1024;
        const __hip_bfloat16* wrow = WcT + (size_t)(pt * 16 + r16) * 2048;
        for (int k0 = 0; k0 < 2048; k0 += 32) {
            bf16x8 a;
            if (k0 < 1024)
                a = *(const bf16x8*)(hrow + k0 + quad * 8);
            else
                a = *(const bf16x8*)&sPool[(mt * 16 + r16) * 1032 + (k0 - 1024) + quad * 8];
            bf16x8 bv = *(const bf16x8*)(wrow + k0 + quad * 8);
            c = mfma16(a, bv, c);
        }
#pragma unroll
        for (int r = 0; r < 4; r++) {
            int t = mt * 16 + quad * 4 + r;
            int p = pt * 16 + r16;
            slg[t * 68 + p] = c[r] + bcomp[p];
        }
    }
    __syncthreads();

    // ---- NLL per t
    if (tid < 32) {
        int t = tid;
        const float* row = &slg[t * 68];
        float m = -3.4e38f;
        for (int p = 0; p < 64; p++) m = fmaxf(m, row[p]);
        float se = 0.f;
        for (int p = 0; p < 64; p++) se += __expf(row[p] - m);
        int a = actions[b * 32 + t];
        nllT[t * 256 + b] = m + __logf(se) - row[a];
    }
}

// ---------------- decoder init: max-pool final states over io examples -------
__global__ __launch_bounds__(256) void kinit_dec(
    const __hip_bfloat16* __restrict__ hf,  // final h (buf0): [2][1024][512]
    const float* __restrict__ cf,
    __hip_bfloat16* __restrict__ h0,        // [256][1024] (hAll[0])
    float* __restrict__ c0)
{
    int idx = blockIdx.x * 256 + threadIdx.x;
    int b = idx >> 10, e = idx & 1023;
    int dir = e >> 9, u = e & 511;
    const __hip_bfloat16* hs = hf + (size_t)dir * 1024 * 512;
    const float* cs = cf + (size_t)dir * 1024 * 512;
    float hv = -3.4e38f, cv = -3.4e38f;
#pragma unroll
    for (int n = 0; n < 4; n++) {
        size_t ix = (size_t)(b * 4 + n) * 512 + u;
        hv = fmaxf(hv, __bfloat162float(hs[ix]));
        cv = fmaxf(cv, cs[ix]);
    }
    h0[idx] = __float2bfloat16(hv);
    c0[idx] = cv;
}

__global__ void kfinal(const float* __restrict__ nllT, void* __restrict__ out,
                       const int* __restrict__ mode) {
    int i = threadIdx.x;
    float s = 0.f;
#pragma unroll
    for (int t = 0; t < 32; t++) s += nllT[t * 256 + i];
    if (*mode) ((__hip_bfloat16*)out)[i] = __float2bfloat16(s);
    else       ((float*)out)[i] = s;
}

// -----------------------------------------------------------------------------
extern "C" void kernel_launch(void* const* d_in, const int* in_sizes, int n_in,
                              void* d_out, int out_size, void* d_ws, size_t ws_size,
                              hipStream_t stream) {
    const int* exs = (const int*)d_in[0];
    const int* cls = (const int*)d_in[1];
    const void* E_raw     = d_in[2];
    const void* WiF_raw   = d_in[3];
    const void* WhF_raw   = d_in[4];
    const void* bF_raw    = d_in[5];
    const void* WiB_raw   = d_in[6];
    const void* WhB_raw   = d_in[7];
    const void* bB_raw    = d_in[8];
    const void* Wattn_raw = d_in[9];
    const void* Wcomp_raw = d_in[10];
    const void* bcomp_raw = d_in[11];
    const void* vWi_raw   = d_in[12];
    const void* vWh_raw   = d_in[13];
    const void* vb_raw    = d_in[14];
    const void* fe_raw    = d_in[15];
    const int* actions = (const int*)d_in[16];
    (void)in_sizes; (void)n_in; (void)out_size; (void)ws_size;

    char* w = (char*)d_ws;
    size_t off = 0;
    auto take = [&](size_t bytes) -> char* {
        char* p = w + off;
        off = (off + bytes + 255) & ~(size_t)255;
        return p;
    };
    __hip_bfloat16* WhT    = (__hip_bfloat16*)take(2ull * 2048 * 512 * 2);
    __hip_bfloat16* WiT    = (__hip_bfloat16*)take(2ull * 2048 * 256 * 2);
    __hip_bfloat16* vWhT   = (__hip_bfloat16*)take(4096ull * 1024 * 2);
    __hip_bfloat16* vWiT   = (__hip_bfloat16*)take(4096ull * 1024 * 2);
    __hip_bfloat16* WattnT = (__hip_bfloat16*)take(1024ull * 1024 * 2);
    __hip_bfloat16* WcT    = (__hip_bfloat16*)take(64ull * 2048 * 2);
    __hip_bfloat16* Ebf    = (__hip_bfloat16*)take(128ull * 128 * 2);
    __hip_bfloat16* febf   = (__hip_bfloat16*)take(32ull * 1024 * 2);
    float* bFf   = (float*)take(2048 * 4);
    float* bBf   = (float*)take(2048 * 4);
    float* bcf   = (float*)take(64 * 4);
    float* vbf   = (float*)take(4096 * 4);
    float* Gtab  = (float*)take(4ull * 128 * 2048 * 4);
    float* VX    = (float*)take(32ull * 4096 * 4);
    __hip_bfloat16* hEnc = (__hip_bfloat16*)take(2ull * 2 * 1024 * 512 * 2); // [buf][dir][1024][512]
    float* cEnc = (float*)take(2ull * 1024 * 512 * 4);
    __hip_bfloat16* hAll = (__hip_bfloat16*)take(33ull * 256 * 1024 * 2);    // h_0..h_32
    float* cDec = (float*)take(256ull * 1024 * 4);
    float* qall = (float*)take(32ull * 256 * 1024 * 4);
    float* nllT = (float*)take(32ull * 256 * 4);
    int*   mode = (int*)take(256);
    unsigned char* ctx8  = (unsigned char*)take(64ull * 1024 * 1024);  // fp8 [l][b4n][e]
    unsigned char* ctxT8 = (unsigned char*)take(64ull * 1024 * 1024);  // fp8 [b4n][e][l]

    (void)hipMemsetAsync(hEnc, 0, 2ull * 1024 * 512 * 2, stream);  // h buf0, both dirs
    (void)hipMemsetAsync(cEnc, 0, 2ull * 1024 * 512 * 4, stream);

    kdetect<<<1, 128, 0, stream>>>((const unsigned int*)E_raw, mode);

    kcvt_bf16<<<64, 256, 0, stream>>>(E_raw,  Ebf,  128 * 128, mode);
    kcvt_bf16<<<128, 256, 0, stream>>>(fe_raw, febf, 32 * 1024, mode);
    kcvt_f32<<<8, 256, 0, stream>>>(bF_raw, bFf, 2048, mode);
    kcvt_f32<<<8, 256, 0, stream>>>(bB_raw, bBf, 2048, mode);
    kcvt_f32<<<1, 256, 0, stream>>>(bcomp_raw, bcf, 64, mode);
    kcvt_f32<<<16, 256, 0, stream>>>(vb_raw, vbf, 4096, mode);

    ktranspose_cvt<<<dim3(32, 8),  256, 0, stream>>>(WhF_raw,   WhT,              512, 2048, mode);
    ktranspose_cvt<<<dim3(32, 8),  256, 0, stream>>>(WhB_raw,   WhT + 2048 * 512, 512, 2048, mode);
    ktranspose_cvt<<<dim3(32, 4),  256, 0, stream>>>(WiF_raw,   WiT,              256, 2048, mode);
    ktranspose_cvt<<<dim3(32, 4),  256, 0, stream>>>(WiB_raw,   WiT + 2048 * 256, 256, 2048, mode);
    ktranspose_cvt<<<dim3(64, 16), 256, 0, stream>>>(vWh_raw,   vWhT,            1024, 4096, mode);
    ktranspose_cvt<<<dim3(64, 16), 256, 0, stream>>>(vWi_raw,   vWiT,            1024, 4096, mode);
    ktranspose_cvt<<<dim3(16, 16), 256, 0, stream>>>(Wattn_raw, WattnT,          1024, 1024, mode);
    ktranspose_cvt<<<dim3(1, 32),  256, 0, stream>>>(Wcomp_raw, WcT,             2048, 64,   mode);

    kprep_gtab<<<256, 256, 0, stream>>>(Ebf, WiT, bFf, bBf, Gtab);
    kprep_vx<<<32, 256, 0, stream>>>(febf, vWiT, vbf, VX);

    const size_t HB = 2ull * 1024 * 512;
    for (int t = 0; t < 64; t++) {
        kenc_step<<<512, 256, 0, stream>>>(t, WhT, Gtab, exs, cls,
                                           hEnc + (size_t)(t & 1) * HB,
                                           hEnc + (size_t)((t + 1) & 1) * HB,
                                           cEnc, ctx8);
    }
    ktrans8<<<dim3(1024, 16), 256, 0, stream>>>(ctx8, ctxT8);
    kinit_dec<<<1024, 256, 0, stream>>>(hEnc, cEnc, hAll, cDec);

    const size_t HD = 256ull * 1024;
    for (int t = 0; t < 32; t++) {
        kdec_gemm<<<256, 256, 0, stream>>>(t, vWhT, WattnT, VX,
                                           hAll + (size_t)t * HD,
                                           hAll + (size_t)(t + 1) * HD,
                                           cDec, qall + (size_t)t * HD);
    }
    kattn_mfma<<<256, 512, 0, stream>>>(qall, ctx8, ctxT8, hAll, WcT, bcf,
                                        actions, nllT);
    kfinal<<<1, 256, 0, stream>>>(nllT, d_out, mode);
}

// Round 6
// 1649.798 us; speedup vs baseline: 1.1289x; 1.0355x over previous
//
#include <hip/hip_runtime.h>
#include <hip/hip_bf16.h>

typedef __bf16 bf16x8 __attribute__((ext_vector_type(8)));
typedef float  f32x4  __attribute__((ext_vector_type(4)));
typedef float  f32x2  __attribute__((ext_vector_type(2)));
typedef unsigned int u32x4 __attribute__((ext_vector_type(4)));
typedef unsigned short ushort_t;
static_assert(sizeof(bf16x8) == 16, "bf16x8 must be 16B");

#define DEV __device__ __forceinline__

DEV f32x4 mfma16(bf16x8 a, bf16x8 b, f32x4 c) {
    return __builtin_amdgcn_mfma_f32_16x16x32_bf16(a, b, c, 0, 0, 0);
}
DEV f32x4 mfma8(long a, long b, f32x4 c) {
    return __builtin_amdgcn_mfma_f32_16x16x32_fp8_fp8(a, b, c, 0, 0, 0);
}
DEV float sigm(float x)   { return 1.0f / (1.0f + __expf(-x)); }
DEV float tanh_f(float x) { return 2.0f / (1.0f + __expf(-2.0f * x)) - 1.0f; }

// async global->LDS, 16B per lane; lds dest must be wave-uniform base (+lane*16)
DEV void glds16(const __hip_bfloat16* g, __hip_bfloat16* l) {
    __builtin_amdgcn_global_load_lds(
        (const __attribute__((address_space(1))) unsigned int*)g,
        (__attribute__((address_space(3))) unsigned int*)l, 16, 0, 0);
}

DEV unsigned char f32_to_fp8(float v) {
    int p = __builtin_amdgcn_cvt_pk_fp8_f32(v, v, 0, false);
    return (unsigned char)(p & 0xFF);
}

// ---------------- dtype detection: 1 = inputs are bf16, 0 = inputs are fp32 --
__global__ __launch_bounds__(128) void kdetect(const unsigned int* __restrict__ raw,
                                               int* __restrict__ mode) {
    __shared__ int cnt;
    if (threadIdx.x == 0) cnt = 0;
    __syncthreads();
    unsigned int w = raw[threadIdx.x];
    unsigned short lo = (unsigned short)(w & 0xFFFFu);
    unsigned int f32bits = ((unsigned int)lo) << 16;
    float v;
    __builtin_memcpy(&v, &f32bits, 4);
    float a = fabsf(v);
    if (a >= 1e-4f && a <= 1.0f) atomicAdd(&cnt, 1);
    __syncthreads();
    if (threadIdx.x == 0) *mode = (cnt >= 64) ? 1 : 0;
}

__global__ __launch_bounds__(256) void kcvt_bf16(const void* __restrict__ src,
                                                 __hip_bfloat16* __restrict__ dst,
                                                 int n, const int* __restrict__ mode) {
    int i = blockIdx.x * 256 + threadIdx.x;
    if (i >= n) return;
    if (*mode) dst[i] = ((const __hip_bfloat16*)src)[i];
    else       dst[i] = __float2bfloat16(((const float*)src)[i]);
}

__global__ __launch_bounds__(256) void kcvt_f32(const void* __restrict__ src,
                                                float* __restrict__ dst,
                                                int n, const int* __restrict__ mode) {
    int i = blockIdx.x * 256 + threadIdx.x;
    if (i >= n) return;
    if (*mode) dst[i] = __bfloat162float(((const __hip_bfloat16*)src)[i]);
    else       dst[i] = ((const float*)src)[i];
}

// --------- tiled transpose + convert: out_bf16[c][r] = (bf16)in[r][c] --------
__global__ __launch_bounds__(256) void ktranspose_cvt(const void* __restrict__ src,
                                                      __hip_bfloat16* __restrict__ out,
                                                      int R, int C,
                                                      const int* __restrict__ mode) {
    __shared__ float tile[64][65];
    int c0 = blockIdx.x * 64, r0 = blockIdx.y * 64;
    int tx = threadIdx.x & 63, ty = threadIdx.x >> 6;
    int m = *mode;
#pragma unroll
    for (int i = ty; i < 64; i += 4) {
        size_t ix = (size_t)(r0 + i) * C + (c0 + tx);
        tile[i][tx] = m ? __bfloat162float(((const __hip_bfloat16*)src)[ix])
                        : ((const float*)src)[ix];
    }
    __syncthreads();
#pragma unroll
    for (int i = ty; i < 64; i += 4)
        out[(size_t)(c0 + i) * R + (r0 + tx)] = __float2bfloat16(tile[tx][i]);
}

// ------ prep: G tables, gate-interleaved: G[dh][v][u<512][g<4] = E@Wi (+b) ---
__global__ __launch_bounds__(256) void kprep_gtab(
    const __hip_bfloat16* __restrict__ E,    // [128][128]
    const __hip_bfloat16* __restrict__ WiT,  // [2][2048][256]
    const float* __restrict__ bF,
    const float* __restrict__ bB,
    float* __restrict__ G)                   // [4][128][512][4]
{
    int dh = blockIdx.x >> 6;
    int dir = dh >> 1, half = dh & 1;
    int m0 = ((blockIdx.x >> 5) & 1) * 64;
    int n0 = (blockIdx.x & 31) * 64;
    int lane = threadIdx.x & 63, wid = threadIdx.x >> 6;
    int wrow = wid >> 1, wcol = wid & 1;
    int r16 = lane & 15, quad = lane >> 4;

    f32x4 acc[2][2] = {};
    const __hip_bfloat16* Ap = E + (size_t)(m0 + wrow * 32 + r16) * 128 + quad * 8;
    const __hip_bfloat16* Bp = WiT + (size_t)dir * 2048 * 256
                             + (size_t)(n0 + wcol * 32 + r16) * 256 + half * 128 + quad * 8;
#pragma unroll
    for (int kb = 0; kb < 128; kb += 32) {
        bf16x8 a0 = *(const bf16x8*)(Ap + kb);
        bf16x8 a1 = *(const bf16x8*)(Ap + 16 * 128 + kb);
        bf16x8 b0 = *(const bf16x8*)(Bp + kb);
        bf16x8 b1 = *(const bf16x8*)(Bp + 16 * 256 + kb);
        acc[0][0] = mfma16(a0, b0, acc[0][0]);
        acc[0][1] = mfma16(a0, b1, acc[0][1]);
        acc[1][0] = mfma16(a1, b0, acc[1][0]);
        acc[1][1] = mfma16(a1, b1, acc[1][1]);
    }
    const float* bias = dir ? bB : bF;
    float* Gt = G + (size_t)dh * 128 * 2048;
#pragma unroll
    for (int rt = 0; rt < 2; rt++)
#pragma unroll
        for (int ct = 0; ct < 2; ct++)
#pragma unroll
            for (int r = 0; r < 4; r++) {
                int mm = m0 + wrow * 32 + rt * 16 + quad * 4 + r;
                int j = n0 + wcol * 32 + ct * 16 + r16;
                float v = acc[rt][ct][r];
                if (half == 0) v += bias[j];
                int g = j >> 9, u = j & 511;
                Gt[((size_t)mm * 512 + u) * 4 + g] = v;
            }
}

// ---------------- prep: VX[t][j] = field_emb @ v_Wi + v_b --------------------
__global__ __launch_bounds__(256) void kprep_vx(
    const __hip_bfloat16* __restrict__ fe,    // [32][1024]
    const __hip_bfloat16* __restrict__ vWiT,  // [4096][1024]
    const float* __restrict__ vb,             // [4096]
    float* __restrict__ VX)                   // [32][4096]
{
    int n0 = blockIdx.x * 128;
    int lane = threadIdx.x & 63, wid = threadIdx.x >> 6;
    int r16 = lane & 15, quad = lane >> 4;
    f32x4 acc[2][2] = {};
    const __hip_bfloat16* Ap = fe + (size_t)r16 * 1024 + quad * 8;
    const __hip_bfloat16* Bp = vWiT + (size_t)(n0 + wid * 32 + r16) * 1024 + quad * 8;
    for (int kb = 0; kb < 1024; kb += 32) {
        bf16x8 a0 = *(const bf16x8*)(Ap + kb);
        bf16x8 a1 = *(const bf16x8*)(Ap + 16 * 1024 + kb);
        bf16x8 b0 = *(const bf16x8*)(Bp + kb);
        bf16x8 b1 = *(const bf16x8*)(Bp + 16 * 1024 + kb);
        acc[0][0] = mfma16(a0, b0, acc[0][0]);
        acc[0][1] = mfma16(a0, b1, acc[0][1]);
        acc[1][0] = mfma16(a1, b0, acc[1][0]);
        acc[1][1] = mfma16(a1, b1, acc[1][1]);
    }
#pragma unroll
    for (int rt = 0; rt < 2; rt++)
#pragma unroll
        for (int ct = 0; ct < 2; ct++)
#pragma unroll
            for (int r = 0; r < 4; r++) {
                int m = rt * 16 + quad * 4 + r;
                int j = n0 + wid * 32 + ct * 16 + r16;
                VX[(size_t)m * 4096 + j] = acc[rt][ct][r] + vb[j];
            }
}

// ======== encoder LSTM step: 512 blocks (dir x 16 mt x 16 us), 64m x 32u =====
// Triple-buffered counted-vmcnt pipeline (T3/T4-lite): prefetch depth 2, so the
// per-iteration wait is vmcnt(6) on loads issued TWO iterations ago (covered by
// ~2 iterations of MFMA) instead of a full vmcnt(0) drain of the just-issued
// prefetch. Safety: stage(j) targets buf j%3, reused only 3 iters later and
// always after a barrier preceded by lgkmcnt(0) (all ds_reads retired).
__global__ __launch_bounds__(256, 2) void kenc_step(
    int t,
    const __hip_bfloat16* __restrict__ WhT,   // [2][2048][512]
    const float* __restrict__ Gtab,           // [4][128][512][4]
    const int* __restrict__ exs,
    const int* __restrict__ cls,
    const __hip_bfloat16* __restrict__ h_in,  // [2][1024][512]
    __hip_bfloat16* __restrict__ h_out,
    float* __restrict__ c_st,                 // [2][1024][512]
    unsigned char* __restrict__ ctx8)         // [64][256][4][1024] fp8 (x16)
{
    __shared__ __align__(16) __hip_bfloat16 sA[3][64 * 64];   // 3 x 8KB
    __shared__ __align__(16) __hip_bfloat16 sB[3][128 * 64];  // 3 x 16KB

    int bid = blockIdx.x;
    int dir = bid >> 8;
    int mt  = (bid >> 4) & 15;
    int us  = bid & 15;
    int l = dir ? (63 - t) : t;
    int m0 = mt * 64, u0 = us * 32;

    int lane = threadIdx.x & 63, w = threadIdx.x >> 6;   // 4 waves
    int wm = w >> 1, wu = w & 1;                          // 2m x 2u
    int r16 = lane & 15, quad = lane >> 4;
    int srow = lane >> 3;
    int scol = ((lane & 7) ^ srow) * 8;   // swizzled global source column

    const __hip_bfloat16* Ab = h_in + (size_t)dir * 1024 * 512;
    const __hip_bfloat16* Bb = WhT + (size_t)dir * 2048 * 512;

    f32x4 acc[4][2] = {};  // [gate][mi]

    auto stage = [&](int buf, int it) {
        int kb = it * 64;
        // A: 64 rows, 8 calls total -> 2 per wave
#pragma unroll
        for (int c = 0; c < 2; c++) {
            int r8 = (w * 2 + c) * 8;
            glds16(Ab + (size_t)(m0 + r8 + srow) * 512 + kb + scol,
                   &sA[buf][r8 * 64]);
        }
        // B: 128 rows (4 gates x 32 u), 16 calls -> 4 per wave
#pragma unroll
        for (int c = 0; c < 4; c++) {
            int rl = (w * 4 + c) * 8;
            int rr = rl + srow;
            int g = rr >> 5, j = rr & 31;
            glds16(Bb + (size_t)(g * 512 + u0 + j) * 512 + kb + scol,
                   &sB[buf][rl * 64]);
        }
    };

    // prologue: 2 K-tiles in flight (6 ops each per wave)
    stage(0, 0);
    stage(1, 1);

    const int sw = r16 & 7;
    const int NIT = 8;  // 512/64
#pragma unroll
    for (int it = 0; it < NIT; it++) {
        // wait for stage(it): everything older than the newest group (6 ops).
        // Final iteration has no younger group -> drain.
        if (it < NIT - 1)
            asm volatile("s_waitcnt vmcnt(6) lgkmcnt(0)" ::: "memory");
        else
            asm volatile("s_waitcnt vmcnt(0) lgkmcnt(0)" ::: "memory");
        __builtin_amdgcn_s_barrier();
        if (it + 2 < NIT) stage((it + 2) % 3, it + 2);
        const int buf = it % 3;   // compile-time after full unroll
#pragma unroll
        for (int k32 = 0; k32 < 64; k32 += 32) {
            int co = (((k32 >> 3) + quad) ^ sw) * 8;   // swizzled ds_read column
            bf16x8 a[2], bf[4];
#pragma unroll
            for (int mi = 0; mi < 2; mi++)
                a[mi] = *(const bf16x8*)&sA[buf][(wm * 32 + mi * 16 + r16) * 64 + co];
#pragma unroll
            for (int g = 0; g < 4; g++)
                bf[g] = *(const bf16x8*)&sB[buf][(g * 32 + wu * 16 + r16) * 64 + co];
#pragma unroll
            for (int g = 0; g < 4; g++)
#pragma unroll
                for (int mi = 0; mi < 2; mi++)
                    acc[g][mi] = mfma16(a[mi], bf[g], acc[g][mi]);
        }
    }

    // epilogue: thread owns u = u0 + wu*16 + r16, 8 m's
    int u = u0 + wu * 16 + r16;
    size_t cbase = (size_t)dir * 1024 * 512;
    const float* GeT = Gtab + (size_t)(dir * 2) * 128 * 2048;
    const float* GcT = GeT + 128 * 2048;
#pragma unroll
    for (int mi = 0; mi < 2; mi++)
#pragma unroll
        for (int r = 0; r < 4; r++) {
            int m = m0 + wm * 32 + mi * 16 + quad * 4 + r;
            int vE = exs[l * 1024 + m], vC = cls[l * 1024 + m];
            f32x4 ge = *(const f32x4*)&GeT[((size_t)vE * 512 + u) * 4];
            f32x4 gc = *(const f32x4*)&GcT[((size_t)vC * 512 + u) * 4];
            float gi = acc[0][mi][r] + ge[0] + gc[0];
            float gf = acc[1][mi][r] + ge[1] + gc[1];
            float gg = acc[2][mi][r] + ge[2] + gc[2];
            float go = acc[3][mi][r] + ge[3] + gc[3];
            size_t cix = cbase + (size_t)m * 512 + u;
            float cn = sigm(gf) * c_st[cix] + sigm(gi) * tanh_f(gg);
            c_st[cix] = cn;
            float hn = sigm(go) * tanh_f(cn);
            h_out[cix] = __float2bfloat16(hn);
            ctx8[(((size_t)l * 256 + (m >> 2)) * 4 + (m & 3)) * 1024 + dir * 512 + u]
                = f32_to_fp8(hn * 16.0f);
        }
}

// ---- fp8 ctx transpose: ctxT8[b4n][e][l] = ctx8[l][b4n][e] ------------------
__global__ __launch_bounds__(256) void ktrans8(const unsigned char* __restrict__ ctx8,
                                               unsigned char* __restrict__ ctxT8) {
    __shared__ unsigned int tile[64][17];   // 64 l-rows x 64 e-bytes (16 u32 + pad)
    int b4n = blockIdx.x;                   // 0..1023
    int e0 = blockIdx.y * 64;               // e-tile
    int tid = threadIdx.x;
#pragma unroll
    for (int pass = 0; pass < 4; pass++) {
        int idx = pass * 256 + tid;
        int l = idx >> 4, c = idx & 15;
        tile[l][c] = *(const unsigned int*)(ctx8 + (size_t)l * (1024 * 1024)
                                            + (size_t)b4n * 1024 + e0 + c * 4);
    }
    __syncthreads();
    const unsigned char* tb = (const unsigned char*)tile;
#pragma unroll
    for (int pass = 0; pass < 4; pass++) {
        int idx = pass * 256 + tid;
        int e = idx >> 4, c = idx & 15;
        unsigned int v = 0;
#pragma unroll
        for (int j = 0; j < 4; j++) {
            unsigned int byte = tb[(size_t)(c * 4 + j) * 68 + e];
            v |= byte << (8 * j);
        }
        *(unsigned int*)(ctxT8 + ((size_t)b4n * 1024 + e0 + e) * 64 + c * 4) = v;
    }
}

// ======== decoder fused GEMM: cell (0..127: 32m x 64u) + q (128..255) ========
__global__ __launch_bounds__(256, 2) void kdec_gemm(
    int t,
    const __hip_bfloat16* __restrict__ vWhT,   // [4096][1024]
    const __hip_bfloat16* __restrict__ WattnT, // [1024][1024]
    const float* __restrict__ VX,              // [32][4096]
    const __hip_bfloat16* __restrict__ h_in,   // [256][1024]  (h_t = hAll[t])
    __hip_bfloat16* __restrict__ h_out,        // [256][1024]  (hAll[t+1])
    float* __restrict__ c_st,                  // [256][1024]
    float* __restrict__ qout)                  // [256][1024]  (qall[t])
{
    __shared__ __align__(16) __hip_bfloat16 sA[2][32 * 64];
    __shared__ __align__(16) __hip_bfloat16 sB[2][256 * 64];

    int bid = blockIdx.x;
    int lane = threadIdx.x & 63, w = threadIdx.x >> 6;
    int r16 = lane & 15, quad = lane >> 4;
    int srow = lane >> 3;
    int scol = ((lane & 7) ^ srow) * 8;   // swizzled global source column
    const int NIT = 16;  // 1024/64
    const int sw = r16 & 7;

    if (bid < 128) {
        int m0 = (bid >> 4) * 32, u0 = (bid & 15) * 64;
        f32x4 acc[4][2] = {};
        auto stage = [&](int buf, int it) {
            int kb = it * 64;
            glds16(h_in + (size_t)(m0 + w * 8 + srow) * 1024 + kb + scol,
                   &sA[buf][(w * 8) * 64]);
#pragma unroll
            for (int c = 0; c < 8; c++) {
                int rl = w * 64 + c * 8;
                int rr = rl + srow;
                int g = rr >> 6, j = rr & 63;
                glds16(vWhT + (size_t)(g * 1024 + u0 + j) * 1024 + kb + scol,
                       &sB[buf][rl * 64]);
            }
        };
        stage(0, 0);
        __syncthreads();
        int buf = 0;
        for (int it = 0; it < NIT; it++) {
            if (it + 1 < NIT) stage(buf ^ 1, it + 1);
#pragma unroll
            for (int k32 = 0; k32 < 64; k32 += 32) {
                int co = (((k32 >> 3) + quad) ^ sw) * 8;
                bf16x8 a[2], bf[4];
#pragma unroll
                for (int mi = 0; mi < 2; mi++)
                    a[mi] = *(const bf16x8*)&sA[buf][(mi * 16 + r16) * 64 + co];
#pragma unroll
                for (int g = 0; g < 4; g++)
                    bf[g] = *(const bf16x8*)&sB[buf][(g * 64 + w * 16 + r16) * 64 + co];
#pragma unroll
                for (int g = 0; g < 4; g++)
#pragma unroll
                    for (int mi = 0; mi < 2; mi++)
                        acc[g][mi] = mfma16(a[mi], bf[g], acc[g][mi]);
            }
            __syncthreads();
            buf ^= 1;
        }
        int u = u0 + w * 16 + r16;
        const float* vx = VX + (size_t)t * 4096;
        float v0 = vx[u], v1 = vx[1024 + u], v2 = vx[2048 + u], v3 = vx[3072 + u];
#pragma unroll
        for (int mi = 0; mi < 2; mi++)
#pragma unroll
            for (int r = 0; r < 4; r++) {
                int m = m0 + mi * 16 + quad * 4 + r;
                float gi = acc[0][mi][r] + v0;
                float gf = acc[1][mi][r] + v1;
                float gg = acc[2][mi][r] + v2;
                float go = acc[3][mi][r] + v3;
                size_t cix = (size_t)m * 1024 + u;
                float cn = sigm(gf) * c_st[cix] + sigm(gi) * tanh_f(gg);
                c_st[cix] = cn;
                h_out[cix] = __float2bfloat16(sigm(go) * tanh_f(cn));
            }
    } else {
        int b2 = bid - 128;
        int m0 = (b2 >> 4) * 32, n0 = (b2 & 15) * 64;
        f32x4 acc[2] = {};
        auto stage = [&](int buf, int it) {
            int kb = it * 64;
            glds16(h_in + (size_t)(m0 + w * 8 + srow) * 1024 + kb + scol,
                   &sA[buf][(w * 8) * 64]);
#pragma unroll
            for (int c = 0; c < 2; c++) {
                int rl = w * 16 + c * 8;
                glds16(WattnT + (size_t)(n0 + rl + srow) * 1024 + kb + scol,
                       &sB[buf][rl * 64]);
            }
        };
        stage(0, 0);
        __syncthreads();
        int buf = 0;
        for (int it = 0; it < NIT; it++) {
            if (it + 1 < NIT) stage(buf ^ 1, it + 1);
#pragma unroll
            for (int k32 = 0; k32 < 64; k32 += 32) {
                int co = (((k32 >> 3) + quad) ^ sw) * 8;
                bf16x8 a[2];
#pragma unroll
                for (int mi = 0; mi < 2; mi++)
                    a[mi] = *(const bf16x8*)&sA[buf][(mi * 16 + r16) * 64 + co];
                bf16x8 bf = *(const bf16x8*)&sB[buf][(w * 16 + r16) * 64 + co];
#pragma unroll
                for (int mi = 0; mi < 2; mi++)
                    acc[mi] = mfma16(a[mi], bf, acc[mi]);
            }
            __syncthreads();
            buf ^= 1;
        }
        int n = n0 + w * 16 + r16;
#pragma unroll
        for (int mi = 0; mi < 2; mi++)
#pragma unroll
            for (int r = 0; r < 4; r++) {
                int m = m0 + mi * 16 + quad * 4 + r;
                qout[(size_t)m * 1024 + n] = acc[mi][r];
            }
    }
}

// ======== MFMA attention: block = b, all 32 t batched ========================
__global__ __launch_bounds__(512, 2) void kattn_mfma(
    const float* __restrict__ qall,           // [32][256][1024]
    const unsigned char* __restrict__ ctx8,   // [64][1024][1024] fp8 (x16)
    const unsigned char* __restrict__ ctxT8,  // [1024][1024][64] fp8 (x16)
    const __hip_bfloat16* __restrict__ hAll,  // [33][256][1024]
    const __hip_bfloat16* __restrict__ WcT,   // [64][2048]
    const float* __restrict__ bcomp,          // [64]
    const int* __restrict__ actions,          // [256][32]
    float* __restrict__ nllT)                 // [32][256]
{
    __shared__ __align__(16) unsigned char sQ8[32 * 1032];   // q fp8 (/4), row stride 1032
    __shared__ float sS[4][32][65];                          // scores
    __shared__ __align__(16) unsigned char sP[4 * 32 * 72];  // P fp8 (x16/S), stride 72
    __shared__ __align__(16) ushort_t sPool[32 * 1032];      // pooled ctx bf16, stride 1032
    __shared__ float slg[32 * 68];                           // logits

    int b = blockIdx.x;
    int tid = threadIdx.x;
    int lane = tid & 63, w = tid >> 6;
    int r16 = lane & 15, quad = lane >> 4;
    const size_t LSTR = 1024 * 1024;

    // ---- phase Q: qall fp32 -> fp8 (x 1/4) into LDS
    for (int i = 0; i < 64; i++) {
        int idx = i * 512 + tid;           // coalesced over tid
        int t = idx >> 10, e = idx & 1023;
        float v = qall[((size_t)t * 256 + b) * 1024 + e] * 0.25f;
        sQ8[t * 1032 + e] = f32_to_fp8(v);
    }
    __syncthreads();

    // ---- GEMM1: wave w -> (n = w>>1, l-half lh = w&1)
    {
        int n = w >> 1, lh = w & 1;
        int l0 = lh * 32;
        f32x4 c[2][2] = {};
        const unsigned char* cbase = ctx8 + (size_t)(b * 4 + n) * 1024;
        for (int k0 = 0; k0 < 1024; k0 += 32) {
            long a[2], bv[2];
#pragma unroll
            for (int mt = 0; mt < 2; mt++)
                __builtin_memcpy(&a[mt], &sQ8[(mt * 16 + r16) * 1032 + k0 + quad * 8], 8);
#pragma unroll
            for (int lt = 0; lt < 2; lt++)
                bv[lt] = *(const long*)(cbase + (size_t)(l0 + lt * 16 + r16) * LSTR
                                        + k0 + quad * 8);
#pragma unroll
            for (int mt = 0; mt < 2; mt++)
#pragma unroll
                for (int lt = 0; lt < 2; lt++)
                    c[mt][lt] = mfma8(a[mt], bv[lt], c[mt][lt]);
        }
#pragma unroll
        for (int mt = 0; mt < 2; mt++)
#pragma unroll
            for (int lt = 0; lt < 2; lt++)
#pragma unroll
                for (int r = 0; r < 4; r++)
                    sS[n][mt * 16 + quad * 4 + r][l0 + lt * 16 + r16] = c[mt][lt][r];
    }
    __syncthreads();

    // ---- softmax over l, P = fp8(16 * p / S). s = D/4 (q was /4, ctx x16).
    if (tid < 128) {
        int n = tid >> 5, t = tid & 31;
        const float* row = &sS[n][t][0];
        float sum = 0.f;
        for (int l = 0; l < 64; l++)
            sum += __expf(fminf(row[l] * 0.25f, 60.f));
        float inv = 16.0f / sum;
        unsigned char* pr = &sP[(n * 32 + t) * 72];
        for (int l = 0; l < 64; l++)
            pr[l] = f32_to_fp8(__expf(fminf(row[l] * 0.25f, 60.f)) * inv);
    }
    __syncthreads();

    // ---- GEMM2: wave w -> e-range [w*128, w*128+128), loop n, pool in regs
    {
        int e0 = w * 128;
        f32x4 pool[2][8];
#pragma unroll
        for (int mt = 0; mt < 2; mt++)
#pragma unroll
            for (int et = 0; et < 8; et++)
#pragma unroll
                for (int r = 0; r < 4; r++) pool[mt][et][r] = -3.4e38f;

        for (int n = 0; n < 4; n++) {
            f32x4 c[2][8] = {};
            const unsigned char* tbase = ctxT8 + (size_t)(b * 4 + n) * 1024 * 64;
#pragma unroll
            for (int k0 = 0; k0 < 64; k0 += 32) {
                long a[2];
#pragma unroll
                for (int mt = 0; mt < 2; mt++)
                    __builtin_memcpy(&a[mt], &sP[(n * 32 + mt * 16 + r16) * 72 + k0 + quad * 8], 8);
#pragma unroll
                for (int et = 0; et < 8; et++) {
                    long bv = *(const long*)(tbase + (size_t)(e0 + et * 16 + r16) * 64
                                             + k0 + quad * 8);
#pragma unroll
                    for (int mt = 0; mt < 2; mt++)
                        c[mt][et] = mfma8(a[mt], bv, c[mt][et]);
                }
            }
#pragma unroll
            for (int mt = 0; mt < 2; mt++)
#pragma unroll
                for (int et = 0; et < 8; et++)
#pragma unroll
                    for (int r = 0; r < 4; r++)
                        pool[mt][et][r] = fmaxf(pool[mt][et][r], c[mt][et][r] * (1.0f / 256.0f));
        }
#pragma unroll
        for (int mt = 0; mt < 2; mt++)
#pragma unroll
            for (int et = 0; et < 8; et++)
#pragma unroll
                for (int r = 0; r < 4; r++) {
                    int t = mt * 16 + quad * 4 + r;
                    int e = e0 + et * 16 + r16;
                    __hip_bfloat16 hb = __float2bfloat16(pool[mt][et][r]);
                    sPool[t * 1032 + e] = *(ushort_t*)&hb;
                }
    }
    __syncthreads();

    // ---- GEMM3 logits: wave w -> (mt = w&1, pt = w>>1)
    {
        int mt = w & 1, pt = w >> 1;
        f32x4 c = {};
        const __hip_bfloat16* hrow = hAll + ((size_t)(mt * 16 + r16) * 256 + b) * 1024;
        const __hip_bfloat16* wrow = WcT + (size_t)(pt * 16 + r16) * 2048;
        for (int k0 = 0; k0 < 2048; k0 += 32) {
            bf16x8 a;
            if (k0 < 1024)
                a = *(const bf16x8*)(hrow + k0 + quad * 8);
            else
                a = *(const bf16x8*)&sPool[(mt * 16 + r16) * 1032 + (k0 - 1024) + quad * 8];
            bf16x8 bv = *(const bf16x8*)(wrow + k0 + quad * 8);
            c = mfma16(a, bv, c);
        }
#pragma unroll
        for (int r = 0; r < 4; r++) {
            int t = mt * 16 + quad * 4 + r;
            int p = pt * 16 + r16;
            slg[t * 68 + p] = c[r] + bcomp[p];
        }
    }
    __syncthreads();

    // ---- NLL per t
    if (tid < 32) {
        int t = tid;
        const float* row = &slg[t * 68];
        float m = -3.4e38f;
        for (int p = 0; p < 64; p++) m = fmaxf(m, row[p]);
        float se = 0.f;
        for (int p = 0; p < 64; p++) se += __expf(row[p] - m);
        int a = actions[b * 32 + t];
        nllT[t * 256 + b] = m + __logf(se) - row[a];
    }
}

// ---------------- decoder init: max-pool final states over io examples -------
__global__ __launch_bounds__(256) void kinit_dec(
    const __hip_bfloat16* __restrict__ hf,  // final h (buf0): [2][1024][512]
    const float* __restrict__ cf,
    __hip_bfloat16* __restrict__ h0,        // [256][1024] (hAll[0])
    float* __restrict__ c0)
{
    int idx = blockIdx.x * 256 + threadIdx.x;
    int b = idx >> 10, e = idx & 1023;
    int dir = e >> 9, u = e & 511;
    const __hip_bfloat16* hs = hf + (size_t)dir * 1024 * 512;
    const float* cs = cf + (size_t)dir * 1024 * 512;
    float hv = -3.4e38f, cv = -3.4e38f;
#pragma unroll
    for (int n = 0; n < 4; n++) {
        size_t ix = (size_t)(b * 4 + n) * 512 + u;
        hv = fmaxf(hv, __bfloat162float(hs[ix]));
        cv = fmaxf(cv, cs[ix]);
    }
    h0[idx] = __float2bfloat16(hv);
    c0[idx] = cv;
}

__global__ void kfinal(const float* __restrict__ nllT, void* __restrict__ out,
                       const int* __restrict__ mode) {
    int i = threadIdx.x;
    float s = 0.f;
#pragma unroll
    for (int t = 0; t < 32; t++) s += nllT[t * 256 + i];
    if (*mode) ((__hip_bfloat16*)out)[i] = __float2bfloat16(s);
    else       ((float*)out)[i] = s;
}

// -----------------------------------------------------------------------------
extern "C" void kernel_launch(void* const* d_in, const int* in_sizes, int n_in,
                              void* d_out, int out_size, void* d_ws, size_t ws_size,
                              hipStream_t stream) {
    const int* exs = (const int*)d_in[0];
    const int* cls = (const int*)d_in[1];
    const void* E_raw     = d_in[2];
    const void* WiF_raw   = d_in[3];
    const void* WhF_raw   = d_in[4];
    const void* bF_raw    = d_in[5];
    const void* WiB_raw   = d_in[6];
    const void* WhB_raw   = d_in[7];
    const void* bB_raw    = d_in[8];
    const void* Wattn_raw = d_in[9];
    const void* Wcomp_raw = d_in[10];
    const void* bcomp_raw = d_in[11];
    const void* vWi_raw   = d_in[12];
    const void* vWh_raw   = d_in[13];
    const void* vb_raw    = d_in[14];
    const void* fe_raw    = d_in[15];
    const int* actions = (const int*)d_in[16];
    (void)in_sizes; (void)n_in; (void)out_size; (void)ws_size;

    char* w = (char*)d_ws;
    size_t off = 0;
    auto take = [&](size_t bytes) -> char* {
        char* p = w + off;
        off = (off + bytes + 255) & ~(size_t)255;
        return p;
    };
    __hip_bfloat16* WhT    = (__hip_bfloat16*)take(2ull * 2048 * 512 * 2);
    __hip_bfloat16* WiT    = (__hip_bfloat16*)take(2ull * 2048 * 256 * 2);
    __hip_bfloat16* vWhT   = (__hip_bfloat16*)take(4096ull * 1024 * 2);
    __hip_bfloat16* vWiT   = (__hip_bfloat16*)take(4096ull * 1024 * 2);
    __hip_bfloat16* WattnT = (__hip_bfloat16*)take(1024ull * 1024 * 2);
    __hip_bfloat16* WcT    = (__hip_bfloat16*)take(64ull * 2048 * 2);
    __hip_bfloat16* Ebf    = (__hip_bfloat16*)take(128ull * 128 * 2);
    __hip_bfloat16* febf   = (__hip_bfloat16*)take(32ull * 1024 * 2);
    float* bFf   = (float*)take(2048 * 4);
    float* bBf   = (float*)take(2048 * 4);
    float* bcf   = (float*)take(64 * 4);
    float* vbf   = (float*)take(4096 * 4);
    float* Gtab  = (float*)take(4ull * 128 * 2048 * 4);
    float* VX    = (float*)take(32ull * 4096 * 4);
    __hip_bfloat16* hEnc = (__hip_bfloat16*)take(2ull * 2 * 1024 * 512 * 2); // [buf][dir][1024][512]
    float* cEnc = (float*)take(2ull * 1024 * 512 * 4);
    __hip_bfloat16* hAll = (__hip_bfloat16*)take(33ull * 256 * 1024 * 2);    // h_0..h_32
    float* cDec = (float*)take(256ull * 1024 * 4);
    float* qall = (float*)take(32ull * 256 * 1024 * 4);
    float* nllT = (float*)take(32ull * 256 * 4);
    int*   mode = (int*)take(256);
    unsigned char* ctx8  = (unsigned char*)take(64ull * 1024 * 1024);  // fp8 [l][b4n][e]
    unsigned char* ctxT8 = (unsigned char*)take(64ull * 1024 * 1024);  // fp8 [b4n][e][l]

    (void)hipMemsetAsync(hEnc, 0, 2ull * 1024 * 512 * 2, stream);  // h buf0, both dirs
    (void)hipMemsetAsync(cEnc, 0, 2ull * 1024 * 512 * 4, stream);

    kdetect<<<1, 128, 0, stream>>>((const unsigned int*)E_raw, mode);

    kcvt_bf16<<<64, 256, 0, stream>>>(E_raw,  Ebf,  128 * 128, mode);
    kcvt_bf16<<<128, 256, 0, stream>>>(fe_raw, febf, 32 * 1024, mode);
    kcvt_f32<<<8, 256, 0, stream>>>(bF_raw, bFf, 2048, mode);
    kcvt_f32<<<8, 256, 0, stream>>>(bB_raw, bBf, 2048, mode);
    kcvt_f32<<<1, 256, 0, stream>>>(bcomp_raw, bcf, 64, mode);
    kcvt_f32<<<16, 256, 0, stream>>>(vb_raw, vbf, 4096, mode);

    ktranspose_cvt<<<dim3(32, 8),  256, 0, stream>>>(WhF_raw,   WhT,              512, 2048, mode);
    ktranspose_cvt<<<dim3(32, 8),  256, 0, stream>>>(WhB_raw,   WhT + 2048 * 512, 512, 2048, mode);
    ktranspose_cvt<<<dim3(32, 4),  256, 0, stream>>>(WiF_raw,   WiT,              256, 2048, mode);
    ktranspose_cvt<<<dim3(32, 4),  256, 0, stream>>>(WiB_raw,   WiT + 2048 * 256, 256, 2048, mode);
    ktranspose_cvt<<<dim3(64, 16), 256, 0, stream>>>(vWh_raw,   vWhT,            1024, 4096, mode);
    ktranspose_cvt<<<dim3(64, 16), 256, 0, stream>>>(vWi_raw,   vWiT,            1024, 4096, mode);
    ktranspose_cvt<<<dim3(16, 16), 256, 0, stream>>>(Wattn_raw, WattnT,          1024, 1024, mode);
    ktranspose_cvt<<<dim3(1, 32),  256, 0, stream>>>(Wcomp_raw, WcT,             2048, 64,   mode);

    kprep_gtab<<<256, 256, 0, stream>>>(Ebf, WiT, bFf, bBf, Gtab);
    kprep_vx<<<32, 256, 0, stream>>>(febf, vWiT, vbf, VX);

    const size_t HB = 2ull * 1024 * 512;
    for (int t = 0; t < 64; t++) {
        kenc_step<<<512, 256, 0, stream>>>(t, WhT, Gtab, exs, cls,
                                           hEnc + (size_t)(t & 1) * HB,
                                           hEnc + (size_t)((t + 1) & 1) * HB,
                                           cEnc, ctx8);
    }
    ktrans8<<<dim3(1024, 16), 256, 0, stream>>>(ctx8, ctxT8);
    kinit_dec<<<1024, 256, 0, stream>>>(hEnc, cEnc, hAll, cDec);

    const size_t HD = 256ull * 1024;
    for (int t = 0; t < 32; t++) {
        kdec_gemm<<<256, 256, 0, stream>>>(t, vWhT, WattnT, VX,
                                           hAll + (size_t)t * HD,
                                           hAll + (size_t)(t + 1) * HD,
                                           cDec, qall + (size_t)t * HD);
    }
    kattn_mfma<<<256, 512, 0, stream>>>(qall, ctx8, ctxT8, hAll, WcT, bcf,
                                        actions, nllT);
    kfinal<<<1, 256, 0, stream>>>(nllT, d_out, mode);
}

// Round 7
// 1587.273 us; speedup vs baseline: 1.1734x; 1.0394x over previous
//
#include <hip/hip_runtime.h>
#include <hip/hip_bf16.h>

typedef __bf16 bf16x8 __attribute__((ext_vector_type(8)));
typedef float  f32x4  __attribute__((ext_vector_type(4)));
typedef float  f32x2  __attribute__((ext_vector_type(2)));
typedef unsigned int u32x4 __attribute__((ext_vector_type(4)));
typedef unsigned short ushort_t;
static_assert(sizeof(bf16x8) == 16, "bf16x8 must be 16B");

#define DEV __device__ __forceinline__

DEV f32x4 mfma16(bf16x8 a, bf16x8 b, f32x4 c) {
    return __builtin_amdgcn_mfma_f32_16x16x32_bf16(a, b, c, 0, 0, 0);
}
DEV f32x4 mfma8(long a, long b, f32x4 c) {
    return __builtin_amdgcn_mfma_f32_16x16x32_fp8_fp8(a, b, c, 0, 0, 0);
}
DEV float sigm(float x)   { return 1.0f / (1.0f + __expf(-x)); }
DEV float tanh_f(float x) { return 2.0f / (1.0f + __expf(-2.0f * x)) - 1.0f; }

// async global->LDS, 16B per lane; lds dest must be wave-uniform base (+lane*16)
DEV void glds16(const __hip_bfloat16* g, __hip_bfloat16* l) {
    __builtin_amdgcn_global_load_lds(
        (const __attribute__((address_space(1))) unsigned int*)g,
        (__attribute__((address_space(3))) unsigned int*)l, 16, 0, 0);
}

DEV unsigned char f32_to_fp8(float v) {
    int p = __builtin_amdgcn_cvt_pk_fp8_f32(v, v, 0, false);
    return (unsigned char)(p & 0xFF);
}

// ---------------- dtype detection: 1 = inputs are bf16, 0 = inputs are fp32 --
__global__ __launch_bounds__(128) void kdetect(const unsigned int* __restrict__ raw,
                                               int* __restrict__ mode) {
    __shared__ int cnt;
    if (threadIdx.x == 0) cnt = 0;
    __syncthreads();
    unsigned int w = raw[threadIdx.x];
    unsigned short lo = (unsigned short)(w & 0xFFFFu);
    unsigned int f32bits = ((unsigned int)lo) << 16;
    float v;
    __builtin_memcpy(&v, &f32bits, 4);
    float a = fabsf(v);
    if (a >= 1e-4f && a <= 1.0f) atomicAdd(&cnt, 1);
    __syncthreads();
    if (threadIdx.x == 0) *mode = (cnt >= 64) ? 1 : 0;
}

__global__ __launch_bounds__(256) void kcvt_bf16(const void* __restrict__ src,
                                                 __hip_bfloat16* __restrict__ dst,
                                                 int n, const int* __restrict__ mode) {
    int i = blockIdx.x * 256 + threadIdx.x;
    if (i >= n) return;
    if (*mode) dst[i] = ((const __hip_bfloat16*)src)[i];
    else       dst[i] = __float2bfloat16(((const float*)src)[i]);
}

__global__ __launch_bounds__(256) void kcvt_f32(const void* __restrict__ src,
                                                float* __restrict__ dst,
                                                int n, const int* __restrict__ mode) {
    int i = blockIdx.x * 256 + threadIdx.x;
    if (i >= n) return;
    if (*mode) dst[i] = __bfloat162float(((const __hip_bfloat16*)src)[i]);
    else       dst[i] = ((const float*)src)[i];
}

// --------- tiled transpose + convert: out_bf16[c][r] = (bf16)in[r][c] --------
__global__ __launch_bounds__(256) void ktranspose_cvt(const void* __restrict__ src,
                                                      __hip_bfloat16* __restrict__ out,
                                                      int R, int C,
                                                      const int* __restrict__ mode) {
    __shared__ float tile[64][65];
    int c0 = blockIdx.x * 64, r0 = blockIdx.y * 64;
    int tx = threadIdx.x & 63, ty = threadIdx.x >> 6;
    int m = *mode;
#pragma unroll
    for (int i = ty; i < 64; i += 4) {
        size_t ix = (size_t)(r0 + i) * C + (c0 + tx);
        tile[i][tx] = m ? __bfloat162float(((const __hip_bfloat16*)src)[ix])
                        : ((const float*)src)[ix];
    }
    __syncthreads();
#pragma unroll
    for (int i = ty; i < 64; i += 4)
        out[(size_t)(c0 + i) * R + (r0 + tx)] = __float2bfloat16(tile[tx][i]);
}

// ------ prep: G tables, gate-interleaved: G[dh][v][u<512][g<4] = E@Wi (+b) ---
__global__ __launch_bounds__(256) void kprep_gtab(
    const __hip_bfloat16* __restrict__ E,    // [128][128]
    const __hip_bfloat16* __restrict__ WiT,  // [2][2048][256]
    const float* __restrict__ bF,
    const float* __restrict__ bB,
    float* __restrict__ G)                   // [4][128][512][4]
{
    int dh = blockIdx.x >> 6;
    int dir = dh >> 1, half = dh & 1;
    int m0 = ((blockIdx.x >> 5) & 1) * 64;
    int n0 = (blockIdx.x & 31) * 64;
    int lane = threadIdx.x & 63, wid = threadIdx.x >> 6;
    int wrow = wid >> 1, wcol = wid & 1;
    int r16 = lane & 15, quad = lane >> 4;

    f32x4 acc[2][2] = {};
    const __hip_bfloat16* Ap = E + (size_t)(m0 + wrow * 32 + r16) * 128 + quad * 8;
    const __hip_bfloat16* Bp = WiT + (size_t)dir * 2048 * 256
                             + (size_t)(n0 + wcol * 32 + r16) * 256 + half * 128 + quad * 8;
#pragma unroll
    for (int kb = 0; kb < 128; kb += 32) {
        bf16x8 a0 = *(const bf16x8*)(Ap + kb);
        bf16x8 a1 = *(const bf16x8*)(Ap + 16 * 128 + kb);
        bf16x8 b0 = *(const bf16x8*)(Bp + kb);
        bf16x8 b1 = *(const bf16x8*)(Bp + 16 * 256 + kb);
        acc[0][0] = mfma16(a0, b0, acc[0][0]);
        acc[0][1] = mfma16(a0, b1, acc[0][1]);
        acc[1][0] = mfma16(a1, b0, acc[1][0]);
        acc[1][1] = mfma16(a1, b1, acc[1][1]);
    }
    const float* bias = dir ? bB : bF;
    float* Gt = G + (size_t)dh * 128 * 2048;
#pragma unroll
    for (int rt = 0; rt < 2; rt++)
#pragma unroll
        for (int ct = 0; ct < 2; ct++)
#pragma unroll
            for (int r = 0; r < 4; r++) {
                int mm = m0 + wrow * 32 + rt * 16 + quad * 4 + r;
                int j = n0 + wcol * 32 + ct * 16 + r16;
                float v = acc[rt][ct][r];
                if (half == 0) v += bias[j];
                int g = j >> 9, u = j & 511;
                Gt[((size_t)mm * 512 + u) * 4 + g] = v;
            }
}

// ---------------- prep: VX[t][j] = field_emb @ v_Wi + v_b --------------------
__global__ __launch_bounds__(256) void kprep_vx(
    const __hip_bfloat16* __restrict__ fe,    // [32][1024]
    const __hip_bfloat16* __restrict__ vWiT,  // [4096][1024]
    const float* __restrict__ vb,             // [4096]
    float* __restrict__ VX)                   // [32][4096]
{
    int n0 = blockIdx.x * 128;
    int lane = threadIdx.x & 63, wid = threadIdx.x >> 6;
    int r16 = lane & 15, quad = lane >> 4;
    f32x4 acc[2][2] = {};
    const __hip_bfloat16* Ap = fe + (size_t)r16 * 1024 + quad * 8;
    const __hip_bfloat16* Bp = vWiT + (size_t)(n0 + wid * 32 + r16) * 1024 + quad * 8;
    for (int kb = 0; kb < 1024; kb += 32) {
        bf16x8 a0 = *(const bf16x8*)(Ap + kb);
        bf16x8 a1 = *(const bf16x8*)(Ap + 16 * 1024 + kb);
        bf16x8 b0 = *(const bf16x8*)(Bp + kb);
        bf16x8 b1 = *(const bf16x8*)(Bp + 16 * 1024 + kb);
        acc[0][0] = mfma16(a0, b0, acc[0][0]);
        acc[0][1] = mfma16(a0, b1, acc[0][1]);
        acc[1][0] = mfma16(a1, b0, acc[1][0]);
        acc[1][1] = mfma16(a1, b1, acc[1][1]);
    }
#pragma unroll
    for (int rt = 0; rt < 2; rt++)
#pragma unroll
        for (int ct = 0; ct < 2; ct++)
#pragma unroll
            for (int r = 0; r < 4; r++) {
                int m = rt * 16 + quad * 4 + r;
                int j = n0 + wid * 32 + ct * 16 + r16;
                VX[(size_t)m * 4096 + j] = acc[rt][ct][r] + vb[j];
            }
}

// ======== encoder LSTM step: 512 blocks (dir x 16 mt x 16 us), 64m x 32u =====
// Triple-buffered counted-vmcnt pipeline (T3/T4-lite): prefetch depth 2, wait
// is vmcnt(6) on loads issued TWO iterations ago. Verified round 6.
__global__ __launch_bounds__(256, 2) void kenc_step(
    int t,
    const __hip_bfloat16* __restrict__ WhT,   // [2][2048][512]
    const float* __restrict__ Gtab,           // [4][128][512][4]
    const int* __restrict__ exs,
    const int* __restrict__ cls,
    const __hip_bfloat16* __restrict__ h_in,  // [2][1024][512]
    __hip_bfloat16* __restrict__ h_out,
    float* __restrict__ c_st,                 // [2][1024][512]
    unsigned char* __restrict__ ctx8)         // [64][256][4][1024] fp8 (x16)
{
    __shared__ __align__(16) __hip_bfloat16 sA[3][64 * 64];   // 3 x 8KB
    __shared__ __align__(16) __hip_bfloat16 sB[3][128 * 64];  // 3 x 16KB

    int bid = blockIdx.x;
    int dir = bid >> 8;
    int mt  = (bid >> 4) & 15;
    int us  = bid & 15;
    int l = dir ? (63 - t) : t;
    int m0 = mt * 64, u0 = us * 32;

    int lane = threadIdx.x & 63, w = threadIdx.x >> 6;   // 4 waves
    int wm = w >> 1, wu = w & 1;                          // 2m x 2u
    int r16 = lane & 15, quad = lane >> 4;
    int srow = lane >> 3;
    int scol = ((lane & 7) ^ srow) * 8;   // swizzled global source column

    const __hip_bfloat16* Ab = h_in + (size_t)dir * 1024 * 512;
    const __hip_bfloat16* Bb = WhT + (size_t)dir * 2048 * 512;

    f32x4 acc[4][2] = {};  // [gate][mi]

    auto stage = [&](int buf, int it) {
        int kb = it * 64;
        // A: 64 rows, 8 calls total -> 2 per wave
#pragma unroll
        for (int c = 0; c < 2; c++) {
            int r8 = (w * 2 + c) * 8;
            glds16(Ab + (size_t)(m0 + r8 + srow) * 512 + kb + scol,
                   &sA[buf][r8 * 64]);
        }
        // B: 128 rows (4 gates x 32 u), 16 calls -> 4 per wave
#pragma unroll
        for (int c = 0; c < 4; c++) {
            int rl = (w * 4 + c) * 8;
            int rr = rl + srow;
            int g = rr >> 5, j = rr & 31;
            glds16(Bb + (size_t)(g * 512 + u0 + j) * 512 + kb + scol,
                   &sB[buf][rl * 64]);
        }
    };

    // prologue: 2 K-tiles in flight (6 ops each per wave)
    stage(0, 0);
    stage(1, 1);

    const int sw = r16 & 7;
    const int NIT = 8;  // 512/64
#pragma unroll
    for (int it = 0; it < NIT; it++) {
        if (it < NIT - 1)
            asm volatile("s_waitcnt vmcnt(6) lgkmcnt(0)" ::: "memory");
        else
            asm volatile("s_waitcnt vmcnt(0) lgkmcnt(0)" ::: "memory");
        __builtin_amdgcn_s_barrier();
        if (it + 2 < NIT) stage((it + 2) % 3, it + 2);
        const int buf = it % 3;   // compile-time after full unroll
#pragma unroll
        for (int k32 = 0; k32 < 64; k32 += 32) {
            int co = (((k32 >> 3) + quad) ^ sw) * 8;   // swizzled ds_read column
            bf16x8 a[2], bf[4];
#pragma unroll
            for (int mi = 0; mi < 2; mi++)
                a[mi] = *(const bf16x8*)&sA[buf][(wm * 32 + mi * 16 + r16) * 64 + co];
#pragma unroll
            for (int g = 0; g < 4; g++)
                bf[g] = *(const bf16x8*)&sB[buf][(g * 32 + wu * 16 + r16) * 64 + co];
#pragma unroll
            for (int g = 0; g < 4; g++)
#pragma unroll
                for (int mi = 0; mi < 2; mi++)
                    acc[g][mi] = mfma16(a[mi], bf[g], acc[g][mi]);
        }
    }

    // epilogue: thread owns u = u0 + wu*16 + r16, 8 m's
    int u = u0 + wu * 16 + r16;
    size_t cbase = (size_t)dir * 1024 * 512;
    const float* GeT = Gtab + (size_t)(dir * 2) * 128 * 2048;
    const float* GcT = GeT + 128 * 2048;
#pragma unroll
    for (int mi = 0; mi < 2; mi++)
#pragma unroll
        for (int r = 0; r < 4; r++) {
            int m = m0 + wm * 32 + mi * 16 + quad * 4 + r;
            int vE = exs[l * 1024 + m], vC = cls[l * 1024 + m];
            f32x4 ge = *(const f32x4*)&GeT[((size_t)vE * 512 + u) * 4];
            f32x4 gc = *(const f32x4*)&GcT[((size_t)vC * 512 + u) * 4];
            float gi = acc[0][mi][r] + ge[0] + gc[0];
            float gf = acc[1][mi][r] + ge[1] + gc[1];
            float gg = acc[2][mi][r] + ge[2] + gc[2];
            float go = acc[3][mi][r] + ge[3] + gc[3];
            size_t cix = cbase + (size_t)m * 512 + u;
            float cn = sigm(gf) * c_st[cix] + sigm(gi) * tanh_f(gg);
            c_st[cix] = cn;
            float hn = sigm(go) * tanh_f(cn);
            h_out[cix] = __float2bfloat16(hn);
            ctx8[(((size_t)l * 256 + (m >> 2)) * 4 + (m & 3)) * 1024 + dir * 512 + u]
                = f32_to_fp8(hn * 16.0f);
        }
}

// ---- fp8 ctx transpose: ctxT8[b4n][e][l] = ctx8[l][b4n][e] ------------------
__global__ __launch_bounds__(256) void ktrans8(const unsigned char* __restrict__ ctx8,
                                               unsigned char* __restrict__ ctxT8) {
    __shared__ unsigned int tile[64][17];   // 64 l-rows x 64 e-bytes (16 u32 + pad)
    int b4n = blockIdx.x;                   // 0..1023
    int e0 = blockIdx.y * 64;               // e-tile
    int tid = threadIdx.x;
#pragma unroll
    for (int pass = 0; pass < 4; pass++) {
        int idx = pass * 256 + tid;
        int l = idx >> 4, c = idx & 15;
        tile[l][c] = *(const unsigned int*)(ctx8 + (size_t)l * (1024 * 1024)
                                            + (size_t)b4n * 1024 + e0 + c * 4);
    }
    __syncthreads();
    const unsigned char* tb = (const unsigned char*)tile;
#pragma unroll
    for (int pass = 0; pass < 4; pass++) {
        int idx = pass * 256 + tid;
        int e = idx >> 4, c = idx & 15;
        unsigned int v = 0;
#pragma unroll
        for (int j = 0; j < 4; j++) {
            unsigned int byte = tb[(size_t)(c * 4 + j) * 68 + e];
            v |= byte << (8 * j);
        }
        *(unsigned int*)(ctxT8 + ((size_t)b4n * 1024 + e0 + e) * 64 + c * 4) = v;
    }
}

// ======== decoder fused GEMM: cell (0..127: 64m x 32u) + q (128..255) ========
// Same triple-buffer counted-vmcnt schedule as kenc_step (verified round 6):
// cell stage = 6 glds16/wave -> vmcnt(6); q stage = 3 -> vmcnt(3). NIT=16.
__global__ __launch_bounds__(256, 2) void kdec_gemm(
    int t,
    const __hip_bfloat16* __restrict__ vWhT,   // [4096][1024]
    const __hip_bfloat16* __restrict__ WattnT, // [1024][1024]
    const float* __restrict__ VX,              // [32][4096]
    const __hip_bfloat16* __restrict__ h_in,   // [256][1024]  (h_t = hAll[t])
    __hip_bfloat16* __restrict__ h_out,        // [256][1024]  (hAll[t+1])
    float* __restrict__ c_st,                  // [256][1024]
    float* __restrict__ qout)                  // [256][1024]  (qall[t])
{
    __shared__ __align__(16) __hip_bfloat16 sA[3][64 * 64];   // 3 x 8KB
    __shared__ __align__(16) __hip_bfloat16 sB[3][128 * 64];  // 3 x 16KB

    int bid = blockIdx.x;
    int lane = threadIdx.x & 63, w = threadIdx.x >> 6;   // 4 waves
    int wm = w >> 1, wu = w & 1;                          // 2m x 2u/2n
    int r16 = lane & 15, quad = lane >> 4;
    int srow = lane >> 3;
    int scol = ((lane & 7) ^ srow) * 8;   // swizzled global source column
    const int NIT = 16;  // 1024/64
    const int sw = r16 & 7;

    bool cellp = bid < 128;
    int b2 = cellp ? bid : bid - 128;
    int m0 = (b2 >> 5) * 64;       // 4 m-tiles of 64
    int n0 = (b2 & 31) * 32;       // 32 u/n-tiles of 32

    if (cellp) {
        f32x4 acc[4][2] = {};
        auto stage = [&](int buf, int it) {
            int kb = it * 64;
#pragma unroll
            for (int c = 0; c < 2; c++) {
                int r8 = (w * 2 + c) * 8;
                glds16(h_in + (size_t)(m0 + r8 + srow) * 1024 + kb + scol,
                       &sA[buf][r8 * 64]);
            }
#pragma unroll
            for (int c = 0; c < 4; c++) {
                int rl = (w * 4 + c) * 8;
                int rr = rl + srow;
                int g = rr >> 5, j = rr & 31;
                glds16(vWhT + (size_t)(g * 1024 + n0 + j) * 1024 + kb + scol,
                       &sB[buf][rl * 64]);
            }
        };
        stage(0, 0);
        stage(1, 1);
#pragma unroll
        for (int it = 0; it < NIT; it++) {
            if (it < NIT - 1)
                asm volatile("s_waitcnt vmcnt(6) lgkmcnt(0)" ::: "memory");
            else
                asm volatile("s_waitcnt vmcnt(0) lgkmcnt(0)" ::: "memory");
            __builtin_amdgcn_s_barrier();
            if (it + 2 < NIT) stage((it + 2) % 3, it + 2);
            const int buf = it % 3;
#pragma unroll
            for (int k32 = 0; k32 < 64; k32 += 32) {
                int co = (((k32 >> 3) + quad) ^ sw) * 8;
                bf16x8 a[2], bf[4];
#pragma unroll
                for (int mi = 0; mi < 2; mi++)
                    a[mi] = *(const bf16x8*)&sA[buf][(wm * 32 + mi * 16 + r16) * 64 + co];
#pragma unroll
                for (int g = 0; g < 4; g++)
                    bf[g] = *(const bf16x8*)&sB[buf][(g * 32 + wu * 16 + r16) * 64 + co];
#pragma unroll
                for (int g = 0; g < 4; g++)
#pragma unroll
                    for (int mi = 0; mi < 2; mi++)
                        acc[g][mi] = mfma16(a[mi], bf[g], acc[g][mi]);
            }
        }
        int u = n0 + wu * 16 + r16;
        const float* vx = VX + (size_t)t * 4096;
        float v0 = vx[u], v1 = vx[1024 + u], v2 = vx[2048 + u], v3 = vx[3072 + u];
#pragma unroll
        for (int mi = 0; mi < 2; mi++)
#pragma unroll
            for (int r = 0; r < 4; r++) {
                int m = m0 + wm * 32 + mi * 16 + quad * 4 + r;
                float gi = acc[0][mi][r] + v0;
                float gf = acc[1][mi][r] + v1;
                float gg = acc[2][mi][r] + v2;
                float go = acc[3][mi][r] + v3;
                size_t cix = (size_t)m * 1024 + u;
                float cn = sigm(gf) * c_st[cix] + sigm(gi) * tanh_f(gg);
                c_st[cix] = cn;
                h_out[cix] = __float2bfloat16(sigm(go) * tanh_f(cn));
            }
    } else {
        f32x4 acc[2] = {};
        auto stage = [&](int buf, int it) {
            int kb = it * 64;
#pragma unroll
            for (int c = 0; c < 2; c++) {
                int r8 = (w * 2 + c) * 8;
                glds16(h_in + (size_t)(m0 + r8 + srow) * 1024 + kb + scol,
                       &sA[buf][r8 * 64]);
            }
            {
                int rl = w * 8;
                glds16(WattnT + (size_t)(n0 + rl + srow) * 1024 + kb + scol,
                       &sB[buf][rl * 64]);
            }
        };
        stage(0, 0);
        stage(1, 1);
#pragma unroll
        for (int it = 0; it < NIT; it++) {
            if (it < NIT - 1)
                asm volatile("s_waitcnt vmcnt(3) lgkmcnt(0)" ::: "memory");
            else
                asm volatile("s_waitcnt vmcnt(0) lgkmcnt(0)" ::: "memory");
            __builtin_amdgcn_s_barrier();
            if (it + 2 < NIT) stage((it + 2) % 3, it + 2);
            const int buf = it % 3;
#pragma unroll
            for (int k32 = 0; k32 < 64; k32 += 32) {
                int co = (((k32 >> 3) + quad) ^ sw) * 8;
                bf16x8 a[2];
#pragma unroll
                for (int mi = 0; mi < 2; mi++)
                    a[mi] = *(const bf16x8*)&sA[buf][(wm * 32 + mi * 16 + r16) * 64 + co];
                bf16x8 bf = *(const bf16x8*)&sB[buf][(wu * 16 + r16) * 64 + co];
#pragma unroll
                for (int mi = 0; mi < 2; mi++)
                    acc[mi] = mfma16(a[mi], bf, acc[mi]);
            }
        }
        int n = n0 + wu * 16 + r16;
#pragma unroll
        for (int mi = 0; mi < 2; mi++)
#pragma unroll
            for (int r = 0; r < 4; r++) {
                int m = m0 + wm * 32 + mi * 16 + quad * 4 + r;
                qout[(size_t)m * 1024 + n] = acc[mi][r];
            }
    }
}

// ======== MFMA attention: block = b, all 32 t batched ========================
__global__ __launch_bounds__(512, 2) void kattn_mfma(
    const float* __restrict__ qall,           // [32][256][1024]
    const unsigned char* __restrict__ ctx8,   // [64][1024][1024] fp8 (x16)
    const unsigned char* __restrict__ ctxT8,  // [1024][1024][64] fp8 (x16)
    const __hip_bfloat16* __restrict__ hAll,  // [33][256][1024]
    const __hip_bfloat16* __restrict__ WcT,   // [64][2048]
    const float* __restrict__ bcomp,          // [64]
    const int* __restrict__ actions,          // [256][32]
    float* __restrict__ nllT)                 // [32][256]
{
    __shared__ __align__(16) unsigned char sQ8[32 * 1032];   // q fp8 (/4), row stride 1032
    __shared__ float sS[4][32][65];                          // scores
    __shared__ __align__(16) unsigned char sP[4 * 32 * 72];  // P fp8 (x16/S), stride 72
    __shared__ __align__(16) ushort_t sPool[32 * 1032];      // pooled ctx bf16, stride 1032
    __shared__ float slg[32 * 68];                           // logits

    int b = blockIdx.x;
    int tid = threadIdx.x;
    int lane = tid & 63, w = tid >> 6;
    int r16 = lane & 15, quad = lane >> 4;
    const size_t LSTR = 1024 * 1024;

    // ---- phase Q: qall fp32 -> fp8 (x 1/4) into LDS
    for (int i = 0; i < 64; i++) {
        int idx = i * 512 + tid;           // coalesced over tid
        int t = idx >> 10, e = idx & 1023;
        float v = qall[((size_t)t * 256 + b) * 1024 + e] * 0.25f;
        sQ8[t * 1032 + e] = f32_to_fp8(v);
    }
    __syncthreads();

    // ---- GEMM1: wave w -> (n = w>>1, l-half lh = w&1)
    {
        int n = w >> 1, lh = w & 1;
        int l0 = lh * 32;
        f32x4 c[2][2] = {};
        const unsigned char* cbase = ctx8 + (size_t)(b * 4 + n) * 1024;
        for (int k0 = 0; k0 < 1024; k0 += 32) {
            long a[2], bv[2];
#pragma unroll
            for (int mt = 0; mt < 2; mt++)
                __builtin_memcpy(&a[mt], &sQ8[(mt * 16 + r16) * 1032 + k0 + quad * 8], 8);
#pragma unroll
            for (int lt = 0; lt < 2; lt++)
                bv[lt] = *(const long*)(cbase + (size_t)(l0 + lt * 16 + r16) * LSTR
                                        + k0 + quad * 8);
#pragma unroll
            for (int mt = 0; mt < 2; mt++)
#pragma unroll
                for (int lt = 0; lt < 2; lt++)
                    c[mt][lt] = mfma8(a[mt], bv[lt], c[mt][lt]);
        }
#pragma unroll
        for (int mt = 0; mt < 2; mt++)
#pragma unroll
            for (int lt = 0; lt < 2; lt++)
#pragma unroll
                for (int r = 0; r < 4; r++)
                    sS[n][mt * 16 + quad * 4 + r][l0 + lt * 16 + r16] = c[mt][lt][r];
    }
    __syncthreads();

    // ---- softmax over l, P = fp8(16 * p / S). s = D/4 (q was /4, ctx x16).
    if (tid < 128) {
        int n = tid >> 5, t = tid & 31;
        const float* row = &sS[n][t][0];
        float sum = 0.f;
        for (int l = 0; l < 64; l++)
            sum += __expf(fminf(row[l] * 0.25f, 60.f));
        float inv = 16.0f / sum;
        unsigned char* pr = &sP[(n * 32 + t) * 72];
        for (int l = 0; l < 64; l++)
            pr[l] = f32_to_fp8(__expf(fminf(row[l] * 0.25f, 60.f)) * inv);
    }
    __syncthreads();

    // ---- GEMM2: wave w -> e-range [w*128, w*128+128), loop n, pool in regs
    {
        int e0 = w * 128;
        f32x4 pool[2][8];
#pragma unroll
        for (int mt = 0; mt < 2; mt++)
#pragma unroll
            for (int et = 0; et < 8; et++)
#pragma unroll
                for (int r = 0; r < 4; r++) pool[mt][et][r] = -3.4e38f;

        for (int n = 0; n < 4; n++) {
            f32x4 c[2][8] = {};
            const unsigned char* tbase = ctxT8 + (size_t)(b * 4 + n) * 1024 * 64;
#pragma unroll
            for (int k0 = 0; k0 < 64; k0 += 32) {
                long a[2];
#pragma unroll
                for (int mt = 0; mt < 2; mt++)
                    __builtin_memcpy(&a[mt], &sP[(n * 32 + mt * 16 + r16) * 72 + k0 + quad * 8], 8);
#pragma unroll
                for (int et = 0; et < 8; et++) {
                    long bv = *(const long*)(tbase + (size_t)(e0 + et * 16 + r16) * 64
                                             + k0 + quad * 8);
#pragma unroll
                    for (int mt = 0; mt < 2; mt++)
                        c[mt][et] = mfma8(a[mt], bv, c[mt][et]);
                }
            }
#pragma unroll
            for (int mt = 0; mt < 2; mt++)
#pragma unroll
                for (int et = 0; et < 8; et++)
#pragma unroll
                    for (int r = 0; r < 4; r++)
                        pool[mt][et][r] = fmaxf(pool[mt][et][r], c[mt][et][r] * (1.0f / 256.0f));
        }
#pragma unroll
        for (int mt = 0; mt < 2; mt++)
#pragma unroll
            for (int et = 0; et < 8; et++)
#pragma unroll
                for (int r = 0; r < 4; r++) {
                    int t = mt * 16 + quad * 4 + r;
                    int e = e0 + et * 16 + r16;
                    __hip_bfloat16 hb = __float2bfloat16(pool[mt][et][r]);
                    sPool[t * 1032 + e] = *(ushort_t*)&hb;
                }
    }
    __syncthreads();

    // ---- GEMM3 logits: wave w -> (mt = w&1, pt = w>>1)
    {
        int mt = w & 1, pt = w >> 1;
        f32x4 c = {};
        const __hip_bfloat16* hrow = hAll + ((size_t)(mt * 16 + r16) * 256 + b) * 1024;
        const __hip_bfloat16* wrow = WcT + (size_t)(pt * 16 + r16) * 2048;
        for (int k0 = 0; k0 < 2048; k0 += 32) {
            bf16x8 a;
            if (k0 < 1024)
                a = *(const bf16x8*)(hrow + k0 + quad * 8);
            else
                a = *(const bf16x8*)&sPool[(mt * 16 + r16) * 1032 + (k0 - 1024) + quad * 8];
            bf16x8 bv = *(const bf16x8*)(wrow + k0 + quad * 8);
            c = mfma16(a, bv, c);
        }
#pragma unroll
        for (int r = 0; r < 4; r++) {
            int t = mt * 16 + quad * 4 + r;
            int p = pt * 16 + r16;
            slg[t * 68 + p] = c[r] + bcomp[p];
        }
    }
    __syncthreads();

    // ---- NLL per t
    if (tid < 32) {
        int t = tid;
        const float* row = &slg[t * 68];
        float m = -3.4e38f;
        for (int p = 0; p < 64; p++) m = fmaxf(m, row[p]);
        float se = 0.f;
        for (int p = 0; p < 64; p++) se += __expf(row[p] - m);
        int a = actions[b * 32 + t];
        nllT[t * 256 + b] = m + __logf(se) - row[a];
    }
}

// ---------------- decoder init: max-pool final states over io examples -------
__global__ __launch_bounds__(256) void kinit_dec(
    const __hip_bfloat16* __restrict__ hf,  // final h (buf0): [2][1024][512]
    const float* __restrict__ cf,
    __hip_bfloat16* __restrict__ h0,        // [256][1024] (hAll[0])
    float* __restrict__ c0)
{
    int idx = blockIdx.x * 256 + threadIdx.x;
    int b = idx >> 10, e = idx & 1023;
    int dir = e >> 9, u = e & 511;
    const __hip_bfloat16* hs = hf + (size_t)dir * 1024 * 512;
    const float* cs = cf + (size_t)dir * 1024 * 512;
    float hv = -3.4e38f, cv = -3.4e38f;
#pragma unroll
    for (int n = 0; n < 4; n++) {
        size_t ix = (size_t)(b * 4 + n) * 512 + u;
        hv = fmaxf(hv, __bfloat162float(hs[ix]));
        cv = fmaxf(cv, cs[ix]);
    }
    h0[idx] = __float2bfloat16(hv);
    c0[idx] = cv;
}

__global__ void kfinal(const float* __restrict__ nllT, void* __restrict__ out,
                       const int* __restrict__ mode) {
    int i = threadIdx.x;
    float s = 0.f;
#pragma unroll
    for (int t = 0; t < 32; t++) s += nllT[t * 256 + i];
    if (*mode) ((__hip_bfloat16*)out)[i] = __float2bfloat16(s);
    else       ((float*)out)[i] = s;
}

// -----------------------------------------------------------------------------
extern "C" void kernel_launch(void* const* d_in, const int* in_sizes, int n_in,
                              void* d_out, int out_size, void* d_ws, size_t ws_size,
                              hipStream_t stream) {
    const int* exs = (const int*)d_in[0];
    const int* cls = (const int*)d_in[1];
    const void* E_raw     = d_in[2];
    const void* WiF_raw   = d_in[3];
    const void* WhF_raw   = d_in[4];
    const void* bF_raw    = d_in[5];
    const void* WiB_raw   = d_in[6];
    const void* WhB_raw   = d_in[7];
    const void* bB_raw    = d_in[8];
    const void* Wattn_raw = d_in[9];
    const void* Wcomp_raw = d_in[10];
    const void* bcomp_raw = d_in[11];
    const void* vWi_raw   = d_in[12];
    const void* vWh_raw   = d_in[13];
    const void* vb_raw    = d_in[14];
    const void* fe_raw    = d_in[15];
    const int* actions = (const int*)d_in[16];
    (void)in_sizes; (void)n_in; (void)out_size; (void)ws_size;

    char* w = (char*)d_ws;
    size_t off = 0;
    auto take = [&](size_t bytes) -> char* {
        char* p = w + off;
        off = (off + bytes + 255) & ~(size_t)255;
        return p;
    };
    __hip_bfloat16* WhT    = (__hip_bfloat16*)take(2ull * 2048 * 512 * 2);
    __hip_bfloat16* WiT    = (__hip_bfloat16*)take(2ull * 2048 * 256 * 2);
    __hip_bfloat16* vWhT   = (__hip_bfloat16*)take(4096ull * 1024 * 2);
    __hip_bfloat16* vWiT   = (__hip_bfloat16*)take(4096ull * 1024 * 2);
    __hip_bfloat16* WattnT = (__hip_bfloat16*)take(1024ull * 1024 * 2);
    __hip_bfloat16* WcT    = (__hip_bfloat16*)take(64ull * 2048 * 2);
    __hip_bfloat16* Ebf    = (__hip_bfloat16*)take(128ull * 128 * 2);
    __hip_bfloat16* febf   = (__hip_bfloat16*)take(32ull * 1024 * 2);
    float* bFf   = (float*)take(2048 * 4);
    float* bBf   = (float*)take(2048 * 4);
    float* bcf   = (float*)take(64 * 4);
    float* vbf   = (float*)take(4096 * 4);
    float* Gtab  = (float*)take(4ull * 128 * 2048 * 4);
    float* VX    = (float*)take(32ull * 4096 * 4);
    __hip_bfloat16* hEnc = (__hip_bfloat16*)take(2ull * 2 * 1024 * 512 * 2); // [buf][dir][1024][512]
    float* cEnc = (float*)take(2ull * 1024 * 512 * 4);
    __hip_bfloat16* hAll = (__hip_bfloat16*)take(33ull * 256 * 1024 * 2);    // h_0..h_32
    float* cDec = (float*)take(256ull * 1024 * 4);
    float* qall = (float*)take(32ull * 256 * 1024 * 4);
    float* nllT = (float*)take(32ull * 256 * 4);
    int*   mode = (int*)take(256);
    unsigned char* ctx8  = (unsigned char*)take(64ull * 1024 * 1024);  // fp8 [l][b4n][e]
    unsigned char* ctxT8 = (unsigned char*)take(64ull * 1024 * 1024);  // fp8 [b4n][e][l]

    (void)hipMemsetAsync(hEnc, 0, 2ull * 1024 * 512 * 2, stream);  // h buf0, both dirs
    (void)hipMemsetAsync(cEnc, 0, 2ull * 1024 * 512 * 4, stream);

    kdetect<<<1, 128, 0, stream>>>((const unsigned int*)E_raw, mode);

    kcvt_bf16<<<64, 256, 0, stream>>>(E_raw,  Ebf,  128 * 128, mode);
    kcvt_bf16<<<128, 256, 0, stream>>>(fe_raw, febf, 32 * 1024, mode);
    kcvt_f32<<<8, 256, 0, stream>>>(bF_raw, bFf, 2048, mode);
    kcvt_f32<<<8, 256, 0, stream>>>(bB_raw, bBf, 2048, mode);
    kcvt_f32<<<1, 256, 0, stream>>>(bcomp_raw, bcf, 64, mode);
    kcvt_f32<<<16, 256, 0, stream>>>(vb_raw, vbf, 4096, mode);

    ktranspose_cvt<<<dim3(32, 8),  256, 0, stream>>>(WhF_raw,   WhT,              512, 2048, mode);
    ktranspose_cvt<<<dim3(32, 8),  256, 0, stream>>>(WhB_raw,   WhT + 2048 * 512, 512, 2048, mode);
    ktranspose_cvt<<<dim3(32, 4),  256, 0, stream>>>(WiF_raw,   WiT,              256, 2048, mode);
    ktranspose_cvt<<<dim3(32, 4),  256, 0, stream>>>(WiB_raw,   WiT + 2048 * 256, 256, 2048, mode);
    ktranspose_cvt<<<dim3(64, 16), 256, 0, stream>>>(vWh_raw,   vWhT,            1024, 4096, mode);
    ktranspose_cvt<<<dim3(64, 16), 256, 0, stream>>>(vWi_raw,   vWiT,            1024, 4096, mode);
    ktranspose_cvt<<<dim3(16, 16), 256, 0, stream>>>(Wattn_raw, WattnT,          1024, 1024, mode);
    ktranspose_cvt<<<dim3(1, 32),  256, 0, stream>>>(Wcomp_raw, WcT,             2048, 64,   mode);

    kprep_gtab<<<256, 256, 0, stream>>>(Ebf, WiT, bFf, bBf, Gtab);
    kprep_vx<<<32, 256, 0, stream>>>(febf, vWiT, vbf, VX);

    const size_t HB = 2ull * 1024 * 512;
    for (int t = 0; t < 64; t++) {
        kenc_step<<<512, 256, 0, stream>>>(t, WhT, Gtab, exs, cls,
                                           hEnc + (size_t)(t & 1) * HB,
                                           hEnc + (size_t)((t + 1) & 1) * HB,
                                           cEnc, ctx8);
    }
    ktrans8<<<dim3(1024, 16), 256, 0, stream>>>(ctx8, ctxT8);
    kinit_dec<<<1024, 256, 0, stream>>>(hEnc, cEnc, hAll, cDec);

    const size_t HD = 256ull * 1024;
    for (int t = 0; t < 32; t++) {
        kdec_gemm<<<256, 256, 0, stream>>>(t, vWhT, WattnT, VX,
                                           hAll + (size_t)t * HD,
                                           hAll + (size_t)(t + 1) * HD,
                                           cDec, qall + (size_t)t * HD);
    }
    kattn_mfma<<<256, 512, 0, stream>>>(qall, ctx8, ctxT8, hAll, WcT, bcf,
                                        actions, nllT);
    kfinal<<<1, 256, 0, stream>>>(nllT, d_out, mode);
}

// Round 8
// 1458.878 us; speedup vs baseline: 1.2767x; 1.0880x over previous
//
#include <hip/hip_runtime.h>
#include <hip/hip_bf16.h>

typedef __bf16 bf16x8 __attribute__((ext_vector_type(8)));
typedef float  f32x4  __attribute__((ext_vector_type(4)));
typedef float  f32x2  __attribute__((ext_vector_type(2)));
typedef unsigned int u32x4 __attribute__((ext_vector_type(4)));
typedef unsigned short ushort_t;
static_assert(sizeof(bf16x8) == 16, "bf16x8 must be 16B");

#define DEV __device__ __forceinline__

DEV f32x4 mfma16(bf16x8 a, bf16x8 b, f32x4 c) {
    return __builtin_amdgcn_mfma_f32_16x16x32_bf16(a, b, c, 0, 0, 0);
}
DEV f32x4 mfma8(long a, long b, f32x4 c) {
    return __builtin_amdgcn_mfma_f32_16x16x32_fp8_fp8(a, b, c, 0, 0, 0);
}
DEV float sigm(float x)   { return 1.0f / (1.0f + __expf(-x)); }
DEV float tanh_f(float x) { return 2.0f / (1.0f + __expf(-2.0f * x)) - 1.0f; }

// async global->LDS, 16B per lane; lds dest must be wave-uniform base (+lane*16)
DEV void glds16(const __hip_bfloat16* g, __hip_bfloat16* l) {
    __builtin_amdgcn_global_load_lds(
        (const __attribute__((address_space(1))) unsigned int*)g,
        (__attribute__((address_space(3))) unsigned int*)l, 16, 0, 0);
}

DEV unsigned char f32_to_fp8(float v) {
    int p = __builtin_amdgcn_cvt_pk_fp8_f32(v, v, 0, false);
    return (unsigned char)(p & 0xFF);
}

DEV int i4get(const int4& v, int r) {
    return r == 0 ? v.x : r == 1 ? v.y : r == 2 ? v.z : v.w;
}

// ---------------- dtype detection: 1 = inputs are bf16, 0 = inputs are fp32 --
__global__ __launch_bounds__(128) void kdetect(const unsigned int* __restrict__ raw,
                                               int* __restrict__ mode) {
    __shared__ int cnt;
    if (threadIdx.x == 0) cnt = 0;
    __syncthreads();
    unsigned int w = raw[threadIdx.x];
    unsigned short lo = (unsigned short)(w & 0xFFFFu);
    unsigned int f32bits = ((unsigned int)lo) << 16;
    float v;
    __builtin_memcpy(&v, &f32bits, 4);
    float a = fabsf(v);
    if (a >= 1e-4f && a <= 1.0f) atomicAdd(&cnt, 1);
    __syncthreads();
    if (threadIdx.x == 0) *mode = (cnt >= 64) ? 1 : 0;
}

// ---------------- fused dtype conversions (6 segments in one launch) ---------
struct CvtArgs {
    const void* src[6];
    void* dst[6];
    int n[6];
    int bf16out[6];
};
__global__ __launch_bounds__(256) void kcvt_all(CvtArgs a, const int* __restrict__ mode) {
    int seg = blockIdx.y;
    int i = blockIdx.x * 256 + threadIdx.x;
    if (i >= a.n[seg]) return;
    int m = *mode;
    if (a.bf16out[seg]) {
        __hip_bfloat16* d = (__hip_bfloat16*)a.dst[seg];
        d[i] = m ? ((const __hip_bfloat16*)a.src[seg])[i]
                 : __float2bfloat16(((const float*)a.src[seg])[i]);
    } else {
        float* d = (float*)a.dst[seg];
        d[i] = m ? __bfloat162float(((const __hip_bfloat16*)a.src[seg])[i])
                 : ((const float*)a.src[seg])[i];
    }
}

// ---------- fused tiled transpose+convert: 8 tensors in one launch -----------
// out_bf16[c][r] = (bf16)in[r][c]; blockIdx.z selects the tensor.
struct TransArgs {
    const void* src[8];
    __hip_bfloat16* dst[8];
    int R[8];
    int C[8];
};
__global__ __launch_bounds__(256) void ktrans_all(TransArgs a, const int* __restrict__ mode) {
    __shared__ float tile[64][65];
    int id = blockIdx.z;
    int R = a.R[id], C = a.C[id];
    int c0 = blockIdx.x * 64, r0 = blockIdx.y * 64;
    if (c0 >= C || r0 >= R) return;
    const void* src = a.src[id];
    __hip_bfloat16* out = a.dst[id];
    int tx = threadIdx.x & 63, ty = threadIdx.x >> 6;
    int m = *mode;
#pragma unroll
    for (int i = ty; i < 64; i += 4) {
        size_t ix = (size_t)(r0 + i) * C + (c0 + tx);
        tile[i][tx] = m ? __bfloat162float(((const __hip_bfloat16*)src)[ix])
                        : ((const float*)src)[ix];
    }
    __syncthreads();
#pragma unroll
    for (int i = ty; i < 64; i += 4)
        out[(size_t)(c0 + i) * R + (r0 + tx)] = __float2bfloat16(tile[tx][i]);
}

// ------ prep: G tables, gate-interleaved: G[dh][v][u<512][g<4] = E@Wi (+b) ---
__global__ __launch_bounds__(256) void kprep_gtab(
    const __hip_bfloat16* __restrict__ E,    // [128][128]
    const __hip_bfloat16* __restrict__ WiT,  // [2][2048][256]
    const float* __restrict__ bF,
    const float* __restrict__ bB,
    float* __restrict__ G)                   // [4][128][512][4]
{
    int dh = blockIdx.x >> 6;
    int dir = dh >> 1, half = dh & 1;
    int m0 = ((blockIdx.x >> 5) & 1) * 64;
    int n0 = (blockIdx.x & 31) * 64;
    int lane = threadIdx.x & 63, wid = threadIdx.x >> 6;
    int wrow = wid >> 1, wcol = wid & 1;
    int r16 = lane & 15, quad = lane >> 4;

    f32x4 acc[2][2] = {};
    const __hip_bfloat16* Ap = E + (size_t)(m0 + wrow * 32 + r16) * 128 + quad * 8;
    const __hip_bfloat16* Bp = WiT + (size_t)dir * 2048 * 256
                             + (size_t)(n0 + wcol * 32 + r16) * 256 + half * 128 + quad * 8;
#pragma unroll
    for (int kb = 0; kb < 128; kb += 32) {
        bf16x8 a0 = *(const bf16x8*)(Ap + kb);
        bf16x8 a1 = *(const bf16x8*)(Ap + 16 * 128 + kb);
        bf16x8 b0 = *(const bf16x8*)(Bp + kb);
        bf16x8 b1 = *(const bf16x8*)(Bp + 16 * 256 + kb);
        acc[0][0] = mfma16(a0, b0, acc[0][0]);
        acc[0][1] = mfma16(a0, b1, acc[0][1]);
        acc[1][0] = mfma16(a1, b0, acc[1][0]);
        acc[1][1] = mfma16(a1, b1, acc[1][1]);
    }
    const float* bias = dir ? bB : bF;
    float* Gt = G + (size_t)dh * 128 * 2048;
#pragma unroll
    for (int rt = 0; rt < 2; rt++)
#pragma unroll
        for (int ct = 0; ct < 2; ct++)
#pragma unroll
            for (int r = 0; r < 4; r++) {
                int mm = m0 + wrow * 32 + rt * 16 + quad * 4 + r;
                int j = n0 + wcol * 32 + ct * 16 + r16;
                float v = acc[rt][ct][r];
                if (half == 0) v += bias[j];
                int g = j >> 9, u = j & 511;
                Gt[((size_t)mm * 512 + u) * 4 + g] = v;
            }
}

// ---------------- prep: VX[t][j] = field_emb @ v_Wi + v_b --------------------
__global__ __launch_bounds__(256) void kprep_vx(
    const __hip_bfloat16* __restrict__ fe,    // [32][1024]
    const __hip_bfloat16* __restrict__ vWiT,  // [4096][1024]
    const float* __restrict__ vb,             // [4096]
    float* __restrict__ VX)                   // [32][4096]
{
    int n0 = blockIdx.x * 128;
    int lane = threadIdx.x & 63, wid = threadIdx.x >> 6;
    int r16 = lane & 15, quad = lane >> 4;
    f32x4 acc[2][2] = {};
    const __hip_bfloat16* Ap = fe + (size_t)r16 * 1024 + quad * 8;
    const __hip_bfloat16* Bp = vWiT + (size_t)(n0 + wid * 32 + r16) * 1024 + quad * 8;
    for (int kb = 0; kb < 1024; kb += 32) {
        bf16x8 a0 = *(const bf16x8*)(Ap + kb);
        bf16x8 a1 = *(const bf16x8*)(Ap + 16 * 1024 + kb);
        bf16x8 b0 = *(const bf16x8*)(Bp + kb);
        bf16x8 b1 = *(const bf16x8*)(Bp + 16 * 1024 + kb);
        acc[0][0] = mfma16(a0, b0, acc[0][0]);
        acc[0][1] = mfma16(a0, b1, acc[0][1]);
        acc[1][0] = mfma16(a1, b0, acc[1][0]);
        acc[1][1] = mfma16(a1, b1, acc[1][1]);
    }
#pragma unroll
    for (int rt = 0; rt < 2; rt++)
#pragma unroll
        for (int ct = 0; ct < 2; ct++)
#pragma unroll
            for (int r = 0; r < 4; r++) {
                int m = rt * 16 + quad * 4 + r;
                int j = n0 + wid * 32 + ct * 16 + r16;
                VX[(size_t)m * 4096 + j] = acc[rt][ct][r] + vb[j];
            }
}

// ======== encoder LSTM step: 512 blocks (dir x 16 mt x 16 us), 64m x 32u =====
// Triple-buffered counted-vmcnt pipeline (verified r6) + epilogue prefetch:
// tokens load at kernel start; Gtab gathers + c_st reads issue at it==NIT-2
// (the free stage slot). Final wait vmcnt(24) counts them: outstanding at
// it==NIT-1 = stage(7)[6] + 16 gathers + 8 c = 30 -> retire 6 oldest = stage(7).
__global__ __launch_bounds__(256, 2) void kenc_step(
    int t,
    const __hip_bfloat16* __restrict__ WhT,   // [2][2048][512]
    const float* __restrict__ Gtab,           // [4][128][512][4]
    const int* __restrict__ exs,
    const int* __restrict__ cls,
    const __hip_bfloat16* __restrict__ h_in,  // [2][1024][512]
    __hip_bfloat16* __restrict__ h_out,
    float* __restrict__ c_st,                 // [2][1024][512]
    unsigned char* __restrict__ ctx8)         // [64][256][4][1024] fp8 (x16)
{
    __shared__ __align__(16) __hip_bfloat16 sA[3][64 * 64];   // 3 x 8KB
    __shared__ __align__(16) __hip_bfloat16 sB[3][128 * 64];  // 3 x 16KB

    int bid = blockIdx.x;
    int dir = bid >> 8;
    int mt  = (bid >> 4) & 15;
    int us  = bid & 15;
    int l = dir ? (63 - t) : t;
    int m0 = mt * 64, u0 = us * 32;

    int lane = threadIdx.x & 63, w = threadIdx.x >> 6;   // 4 waves
    int wm = w >> 1, wu = w & 1;                          // 2m x 2u
    int r16 = lane & 15, quad = lane >> 4;
    int srow = lane >> 3;
    int scol = ((lane & 7) ^ srow) * 8;   // swizzled global source column

    const __hip_bfloat16* Ab = h_in + (size_t)dir * 1024 * 512;
    const __hip_bfloat16* Bb = WhT + (size_t)dir * 2048 * 512;

    int u = u0 + wu * 16 + r16;
    int mbase = m0 + wm * 32;
    size_t cbase = (size_t)dir * 1024 * 512;
    const float* GeT = Gtab + (size_t)(dir * 2) * 128 * 2048;
    const float* GcT = GeT + 128 * 2048;

    // token prefetch (fast L2 loads; retire before iter-0's counted wait)
    int4 tE0 = *(const int4*)&exs[l * 1024 + mbase + quad * 4];
    int4 tE1 = *(const int4*)&exs[l * 1024 + mbase + 16 + quad * 4];
    int4 tC0 = *(const int4*)&cls[l * 1024 + mbase + quad * 4];
    int4 tC1 = *(const int4*)&cls[l * 1024 + mbase + 16 + quad * 4];

    f32x4 acc[4][2] = {};  // [gate][mi]
    f32x4 geP[2][4], gcP[2][4];
    float cP[2][4];

    auto stage = [&](int buf, int it) {
        int kb = it * 64;
#pragma unroll
        for (int c = 0; c < 2; c++) {
            int r8 = (w * 2 + c) * 8;
            glds16(Ab + (size_t)(m0 + r8 + srow) * 512 + kb + scol,
                   &sA[buf][r8 * 64]);
        }
#pragma unroll
        for (int c = 0; c < 4; c++) {
            int rl = (w * 4 + c) * 8;
            int rr = rl + srow;
            int g = rr >> 5, j = rr & 31;
            glds16(Bb + (size_t)(g * 512 + u0 + j) * 512 + kb + scol,
                   &sB[buf][rl * 64]);
        }
    };

    // prologue: 2 K-tiles in flight (6 ops each per wave)
    stage(0, 0);
    stage(1, 1);

    const int sw = r16 & 7;
    const int NIT = 8;  // 512/64
#pragma unroll
    for (int it = 0; it < NIT; it++) {
        if (it < NIT - 1)
            asm volatile("s_waitcnt vmcnt(6) lgkmcnt(0)" ::: "memory");
        else
            asm volatile("s_waitcnt vmcnt(24) lgkmcnt(0)" ::: "memory");
        __builtin_amdgcn_s_barrier();
        if (it + 2 < NIT) {
            stage((it + 2) % 3, it + 2);
        } else if (it == NIT - 2) {
            // issue epilogue loads: 16 Gtab gathers + 8 c_st reads (24 VMEM)
#pragma unroll
            for (int mi = 0; mi < 2; mi++)
#pragma unroll
                for (int r = 0; r < 4; r++) {
                    int vE = i4get(mi ? tE1 : tE0, r);
                    int vC = i4get(mi ? tC1 : tC0, r);
                    geP[mi][r] = *(const f32x4*)&GeT[((size_t)vE * 512 + u) * 4];
                    gcP[mi][r] = *(const f32x4*)&GcT[((size_t)vC * 512 + u) * 4];
                    int m = mbase + mi * 16 + quad * 4 + r;
                    cP[mi][r] = c_st[cbase + (size_t)m * 512 + u];
                }
        }
        const int buf = it % 3;   // compile-time after full unroll
#pragma unroll
        for (int k32 = 0; k32 < 64; k32 += 32) {
            int co = (((k32 >> 3) + quad) ^ sw) * 8;   // swizzled ds_read column
            bf16x8 a[2], bf[4];
#pragma unroll
            for (int mi = 0; mi < 2; mi++)
                a[mi] = *(const bf16x8*)&sA[buf][(wm * 32 + mi * 16 + r16) * 64 + co];
#pragma unroll
            for (int g = 0; g < 4; g++)
                bf[g] = *(const bf16x8*)&sB[buf][(g * 32 + wu * 16 + r16) * 64 + co];
#pragma unroll
            for (int g = 0; g < 4; g++)
#pragma unroll
                for (int mi = 0; mi < 2; mi++)
                    acc[g][mi] = mfma16(a[mi], bf[g], acc[g][mi]);
        }
    }

    // epilogue: thread owns u, 8 m's; all inputs prefetched
#pragma unroll
    for (int mi = 0; mi < 2; mi++)
#pragma unroll
        for (int r = 0; r < 4; r++) {
            int m = mbase + mi * 16 + quad * 4 + r;
            f32x4 ge = geP[mi][r];
            f32x4 gc = gcP[mi][r];
            float gi = acc[0][mi][r] + ge[0] + gc[0];
            float gf = acc[1][mi][r] + ge[1] + gc[1];
            float gg = acc[2][mi][r] + ge[2] + gc[2];
            float go = acc[3][mi][r] + ge[3] + gc[3];
            size_t cix = cbase + (size_t)m * 512 + u;
            float cn = sigm(gf) * cP[mi][r] + sigm(gi) * tanh_f(gg);
            c_st[cix] = cn;
            float hn = sigm(go) * tanh_f(cn);
            h_out[cix] = __float2bfloat16(hn);
            ctx8[(((size_t)l * 256 + (m >> 2)) * 4 + (m & 3)) * 1024 + dir * 512 + u]
                = f32_to_fp8(hn * 16.0f);
        }
}

// ---- fp8 ctx transpose: ctxT8[b4n][e][l] = ctx8[l][b4n][e] ------------------
__global__ __launch_bounds__(256) void ktrans8(const unsigned char* __restrict__ ctx8,
                                               unsigned char* __restrict__ ctxT8) {
    __shared__ unsigned int tile[64][17];   // 64 l-rows x 64 e-bytes (16 u32 + pad)
    int b4n = blockIdx.x;                   // 0..1023
    int e0 = blockIdx.y * 64;               // e-tile
    int tid = threadIdx.x;
#pragma unroll
    for (int pass = 0; pass < 4; pass++) {
        int idx = pass * 256 + tid;
        int l = idx >> 4, c = idx & 15;
        tile[l][c] = *(const unsigned int*)(ctx8 + (size_t)l * (1024 * 1024)
                                            + (size_t)b4n * 1024 + e0 + c * 4);
    }
    __syncthreads();
    const unsigned char* tb = (const unsigned char*)tile;
#pragma unroll
    for (int pass = 0; pass < 4; pass++) {
        int idx = pass * 256 + tid;
        int e = idx >> 4, c = idx & 15;
        unsigned int v = 0;
#pragma unroll
        for (int j = 0; j < 4; j++) {
            unsigned int byte = tb[(size_t)(c * 4 + j) * 68 + e];
            v |= byte << (8 * j);
        }
        *(unsigned int*)(ctxT8 + ((size_t)b4n * 1024 + e0 + e) * 64 + c * 4) = v;
    }
}

// ======== decoder fused GEMM: cell (0..127: 64m x 32u) + q (128..255) ========
// Cell: counted-vmcnt pipeline + epilogue prefetch (4 VX + 8 c_st at it==14,
// final wait vmcnt(12)). Q: counted vmcnt(3) pipeline (verified r7).
__global__ __launch_bounds__(256, 2) void kdec_gemm(
    int t,
    const __hip_bfloat16* __restrict__ vWhT,   // [4096][1024]
    const __hip_bfloat16* __restrict__ WattnT, // [1024][1024]
    const float* __restrict__ VX,              // [32][4096]
    const __hip_bfloat16* __restrict__ h_in,   // [256][1024]  (h_t = hAll[t])
    __hip_bfloat16* __restrict__ h_out,        // [256][1024]  (hAll[t+1])
    float* __restrict__ c_st,                  // [256][1024]
    float* __restrict__ qout)                  // [256][1024]  (qall[t])
{
    __shared__ __align__(16) __hip_bfloat16 sA[3][64 * 64];   // 3 x 8KB
    __shared__ __align__(16) __hip_bfloat16 sB[3][128 * 64];  // 3 x 16KB

    int bid = blockIdx.x;
    int lane = threadIdx.x & 63, w = threadIdx.x >> 6;   // 4 waves
    int wm = w >> 1, wu = w & 1;                          // 2m x 2u/2n
    int r16 = lane & 15, quad = lane >> 4;
    int srow = lane >> 3;
    int scol = ((lane & 7) ^ srow) * 8;   // swizzled global source column
    const int NIT = 16;  // 1024/64
    const int sw = r16 & 7;

    bool cellp = bid < 128;
    int b2 = cellp ? bid : bid - 128;
    int m0 = (b2 >> 5) * 64;       // 4 m-tiles of 64
    int n0 = (b2 & 31) * 32;       // 32 u/n-tiles of 32
    int u = n0 + wu * 16 + r16;
    int mbase = m0 + wm * 32;

    if (cellp) {
        f32x4 acc[4][2] = {};
        float vxP[4], cP[2][4];
        const float* vx = VX + (size_t)t * 4096;
        auto stage = [&](int buf, int it) {
            int kb = it * 64;
#pragma unroll
            for (int c = 0; c < 2; c++) {
                int r8 = (w * 2 + c) * 8;
                glds16(h_in + (size_t)(m0 + r8 + srow) * 1024 + kb + scol,
                       &sA[buf][r8 * 64]);
            }
#pragma unroll
            for (int c = 0; c < 4; c++) {
                int rl = (w * 4 + c) * 8;
                int rr = rl + srow;
                int g = rr >> 5, j = rr & 31;
                glds16(vWhT + (size_t)(g * 1024 + n0 + j) * 1024 + kb + scol,
                       &sB[buf][rl * 64]);
            }
        };
        stage(0, 0);
        stage(1, 1);
#pragma unroll
        for (int it = 0; it < NIT; it++) {
            if (it < NIT - 1)
                asm volatile("s_waitcnt vmcnt(6) lgkmcnt(0)" ::: "memory");
            else
                asm volatile("s_waitcnt vmcnt(12) lgkmcnt(0)" ::: "memory");
            __builtin_amdgcn_s_barrier();
            if (it + 2 < NIT) {
                stage((it + 2) % 3, it + 2);
            } else if (it == NIT - 2) {
                // issue epilogue loads: 4 VX + 8 c_st (12 VMEM)
                vxP[0] = vx[u];
                vxP[1] = vx[1024 + u];
                vxP[2] = vx[2048 + u];
                vxP[3] = vx[3072 + u];
#pragma unroll
                for (int mi = 0; mi < 2; mi++)
#pragma unroll
                    for (int r = 0; r < 4; r++) {
                        int m = mbase + mi * 16 + quad * 4 + r;
                        cP[mi][r] = c_st[(size_t)m * 1024 + u];
                    }
            }
            const int buf = it % 3;
#pragma unroll
            for (int k32 = 0; k32 < 64; k32 += 32) {
                int co = (((k32 >> 3) + quad) ^ sw) * 8;
                bf16x8 a[2], bf[4];
#pragma unroll
                for (int mi = 0; mi < 2; mi++)
                    a[mi] = *(const bf16x8*)&sA[buf][(wm * 32 + mi * 16 + r16) * 64 + co];
#pragma unroll
                for (int g = 0; g < 4; g++)
                    bf[g] = *(const bf16x8*)&sB[buf][(g * 32 + wu * 16 + r16) * 64 + co];
#pragma unroll
                for (int g = 0; g < 4; g++)
#pragma unroll
                    for (int mi = 0; mi < 2; mi++)
                        acc[g][mi] = mfma16(a[mi], bf[g], acc[g][mi]);
            }
        }
#pragma unroll
        for (int mi = 0; mi < 2; mi++)
#pragma unroll
            for (int r = 0; r < 4; r++) {
                int m = mbase + mi * 16 + quad * 4 + r;
                float gi = acc[0][mi][r] + vxP[0];
                float gf = acc[1][mi][r] + vxP[1];
                float gg = acc[2][mi][r] + vxP[2];
                float go = acc[3][mi][r] + vxP[3];
                size_t cix = (size_t)m * 1024 + u;
                float cn = sigm(gf) * cP[mi][r] + sigm(gi) * tanh_f(gg);
                c_st[cix] = cn;
                h_out[cix] = __float2bfloat16(sigm(go) * tanh_f(cn));
            }
    } else {
        f32x4 acc[2] = {};
        auto stage = [&](int buf, int it) {
            int kb = it * 64;
#pragma unroll
            for (int c = 0; c < 2; c++) {
                int r8 = (w * 2 + c) * 8;
                glds16(h_in + (size_t)(m0 + r8 + srow) * 1024 + kb + scol,
                       &sA[buf][r8 * 64]);
            }
            {
                int rl = w * 8;
                glds16(WattnT + (size_t)(n0 + rl + srow) * 1024 + kb + scol,
                       &sB[buf][rl * 64]);
            }
        };
        stage(0, 0);
        stage(1, 1);
#pragma unroll
        for (int it = 0; it < NIT; it++) {
            if (it < NIT - 1)
                asm volatile("s_waitcnt vmcnt(3) lgkmcnt(0)" ::: "memory");
            else
                asm volatile("s_waitcnt vmcnt(0) lgkmcnt(0)" ::: "memory");
            __builtin_amdgcn_s_barrier();
            if (it + 2 < NIT) stage((it + 2) % 3, it + 2);
            const int buf = it % 3;
#pragma unroll
            for (int k32 = 0; k32 < 64; k32 += 32) {
                int co = (((k32 >> 3) + quad) ^ sw) * 8;
                bf16x8 a[2];
#pragma unroll
                for (int mi = 0; mi < 2; mi++)
                    a[mi] = *(const bf16x8*)&sA[buf][(wm * 32 + mi * 16 + r16) * 64 + co];
                bf16x8 bf = *(const bf16x8*)&sB[buf][(wu * 16 + r16) * 64 + co];
#pragma unroll
                for (int mi = 0; mi < 2; mi++)
                    acc[mi] = mfma16(a[mi], bf, acc[mi]);
            }
        }
        int n = n0 + wu * 16 + r16;
#pragma unroll
        for (int mi = 0; mi < 2; mi++)
#pragma unroll
            for (int r = 0; r < 4; r++) {
                int m = mbase + mi * 16 + quad * 4 + r;
                qout[(size_t)m * 1024 + n] = acc[mi][r];
            }
    }
}

// ======== MFMA attention: block = b, all 32 t batched ========================
__global__ __launch_bounds__(512, 2) void kattn_mfma(
    const float* __restrict__ qall,           // [32][256][1024]
    const unsigned char* __restrict__ ctx8,   // [64][1024][1024] fp8 (x16)
    const unsigned char* __restrict__ ctxT8,  // [1024][1024][64] fp8 (x16)
    const __hip_bfloat16* __restrict__ hAll,  // [33][256][1024]
    const __hip_bfloat16* __restrict__ WcT,   // [64][2048]
    const float* __restrict__ bcomp,          // [64]
    const int* __restrict__ actions,          // [256][32]
    float* __restrict__ nllT)                 // [32][256]
{
    __shared__ __align__(16) unsigned char sQ8[32 * 1032];   // q fp8 (/4), row stride 1032
    __shared__ float sS[4][32][65];                          // scores
    __shared__ __align__(16) unsigned char sP[4 * 32 * 72];  // P fp8 (x16/S), stride 72
    __shared__ __align__(16) ushort_t sPool[32 * 1032];      // pooled ctx bf16, stride 1032
    __shared__ float slg[32 * 68];                           // logits

    int b = blockIdx.x;
    int tid = threadIdx.x;
    int lane = tid & 63, w = tid >> 6;
    int r16 = lane & 15, quad = lane >> 4;
    const size_t LSTR = 1024 * 1024;

    // ---- phase Q: qall fp32 -> fp8 (x 1/4) into LDS
    for (int i = 0; i < 64; i++) {
        int idx = i * 512 + tid;           // coalesced over tid
        int t = idx >> 10, e = idx & 1023;
        float v = qall[((size_t)t * 256 + b) * 1024 + e] * 0.25f;
        sQ8[t * 1032 + e] = f32_to_fp8(v);
    }
    __syncthreads();

    // ---- GEMM1: wave w -> (n = w>>1, l-half lh = w&1)
    {
        int n = w >> 1, lh = w & 1;
        int l0 = lh * 32;
        f32x4 c[2][2] = {};
        const unsigned char* cbase = ctx8 + (size_t)(b * 4 + n) * 1024;
        for (int k0 = 0; k0 < 1024; k0 += 32) {
            long a[2], bv[2];
#pragma unroll
            for (int mt = 0; mt < 2; mt++)
                __builtin_memcpy(&a[mt], &sQ8[(mt * 16 + r16) * 1032 + k0 + quad * 8], 8);
#pragma unroll
            for (int lt = 0; lt < 2; lt++)
                bv[lt] = *(const long*)(cbase + (size_t)(l0 + lt * 16 + r16) * LSTR
                                        + k0 + quad * 8);
#pragma unroll
            for (int mt = 0; mt < 2; mt++)
#pragma unroll
                for (int lt = 0; lt < 2; lt++)
                    c[mt][lt] = mfma8(a[mt], bv[lt], c[mt][lt]);
        }
#pragma unroll
        for (int mt = 0; mt < 2; mt++)
#pragma unroll
            for (int lt = 0; lt < 2; lt++)
#pragma unroll
                for (int r = 0; r < 4; r++)
                    sS[n][mt * 16 + quad * 4 + r][l0 + lt * 16 + r16] = c[mt][lt][r];
    }
    __syncthreads();

    // ---- softmax over l, P = fp8(16 * p / S). s = D/4 (q was /4, ctx x16).
    if (tid < 128) {
        int n = tid >> 5, t = tid & 31;
        const float* row = &sS[n][t][0];
        float sum = 0.f;
        for (int l = 0; l < 64; l++)
            sum += __expf(fminf(row[l] * 0.25f, 60.f));
        float inv = 16.0f / sum;
        unsigned char* pr = &sP[(n * 32 + t) * 72];
        for (int l = 0; l < 64; l++)
            pr[l] = f32_to_fp8(__expf(fminf(row[l] * 0.25f, 60.f)) * inv);
    }
    __syncthreads();

    // ---- GEMM2: wave w -> e-range [w*128, w*128+128), loop n, pool in regs
    {
        int e0 = w * 128;
        f32x4 pool[2][8];
#pragma unroll
        for (int mt = 0; mt < 2; mt++)
#pragma unroll
            for (int et = 0; et < 8; et++)
#pragma unroll
                for (int r = 0; r < 4; r++) pool[mt][et][r] = -3.4e38f;

        for (int n = 0; n < 4; n++) {
            f32x4 c[2][8] = {};
            const unsigned char* tbase = ctxT8 + (size_t)(b * 4 + n) * 1024 * 64;
#pragma unroll
            for (int k0 = 0; k0 < 64; k0 += 32) {
                long a[2];
#pragma unroll
                for (int mt = 0; mt < 2; mt++)
                    __builtin_memcpy(&a[mt], &sP[(n * 32 + mt * 16 + r16) * 72 + k0 + quad * 8], 8);
#pragma unroll
                for (int et = 0; et < 8; et++) {
                    long bv = *(const long*)(tbase + (size_t)(e0 + et * 16 + r16) * 64
                                             + k0 + quad * 8);
#pragma unroll
                    for (int mt = 0; mt < 2; mt++)
                        c[mt][et] = mfma8(a[mt], bv, c[mt][et]);
                }
            }
#pragma unroll
            for (int mt = 0; mt < 2; mt++)
#pragma unroll
                for (int et = 0; et < 8; et++)
#pragma unroll
                    for (int r = 0; r < 4; r++)
                        pool[mt][et][r] = fmaxf(pool[mt][et][r], c[mt][et][r] * (1.0f / 256.0f));
        }
#pragma unroll
        for (int mt = 0; mt < 2; mt++)
#pragma unroll
            for (int et = 0; et < 8; et++)
#pragma unroll
                for (int r = 0; r < 4; r++) {
                    int t = mt * 16 + quad * 4 + r;
                    int e = e0 + et * 16 + r16;
                    __hip_bfloat16 hb = __float2bfloat16(pool[mt][et][r]);
                    sPool[t * 1032 + e] = *(ushort_t*)&hb;
                }
    }
    __syncthreads();

    // ---- GEMM3 logits: wave w -> (mt = w&1, pt = w>>1)
    {
        int mt = w & 1, pt = w >> 1;
        f32x4 c = {};
        const __hip_bfloat16* hrow = hAll + ((size_t)(mt * 16 + r16) * 256 + b) * 1024;
        const __hip_bfloat16* wrow = WcT + (size_t)(pt * 16 + r16) * 2048;
        for (int k0 = 0; k0 < 2048; k0 += 32) {
            bf16x8 a;
            if (k0 < 1024)
                a = *(const bf16x8*)(hrow + k0 + quad * 8);
            else
                a = *(const bf16x8*)&sPool[(mt * 16 + r16) * 1032 + (k0 - 1024) + quad * 8];
            bf16x8 bv = *(const bf16x8*)(wrow + k0 + quad * 8);
            c = mfma16(a, bv, c);
        }
#pragma unroll
        for (int r = 0; r < 4; r++) {
            int t = mt * 16 + quad * 4 + r;
            int p = pt * 16 + r16;
            slg[t * 68 + p] = c[r] + bcomp[p];
        }
    }
    __syncthreads();

    // ---- NLL per t
    if (tid < 32) {
        int t = tid;
        const float* row = &slg[t * 68];
        float m = -3.4e38f;
        for (int p = 0; p < 64; p++) m = fmaxf(m, row[p]);
        float se = 0.f;
        for (int p = 0; p < 64; p++) se += __expf(row[p] - m);
        int a = actions[b * 32 + t];
        nllT[t * 256 + b] = m + __logf(se) - row[a];
    }
}

// ---------------- decoder init: max-pool final states over io examples -------
__global__ __launch_bounds__(256) void kinit_dec(
    const __hip_bfloat16* __restrict__ hf,  // final h (buf0): [2][1024][512]
    const float* __restrict__ cf,
    __hip_bfloat16* __restrict__ h0,        // [256][1024] (hAll[0])
    float* __restrict__ c0)
{
    int idx = blockIdx.x * 256 + threadIdx.x;
    int b = idx >> 10, e = idx & 1023;
    int dir = e >> 9, u = e & 511;
    const __hip_bfloat16* hs = hf + (size_t)dir * 1024 * 512;
    const float* cs = cf + (size_t)dir * 1024 * 512;
    float hv = -3.4e38f, cv = -3.4e38f;
#pragma unroll
    for (int n = 0; n < 4; n++) {
        size_t ix = (size_t)(b * 4 + n) * 512 + u;
        hv = fmaxf(hv, __bfloat162float(hs[ix]));
        cv = fmaxf(cv, cs[ix]);
    }
    h0[idx] = __float2bfloat16(hv);
    c0[idx] = cv;
}

__global__ void kfinal(const float* __restrict__ nllT, void* __restrict__ out,
                       const int* __restrict__ mode) {
    int i = threadIdx.x;
    float s = 0.f;
#pragma unroll
    for (int t = 0; t < 32; t++) s += nllT[t * 256 + i];
    if (*mode) ((__hip_bfloat16*)out)[i] = __float2bfloat16(s);
    else       ((float*)out)[i] = s;
}

// -----------------------------------------------------------------------------
extern "C" void kernel_launch(void* const* d_in, const int* in_sizes, int n_in,
                              void* d_out, int out_size, void* d_ws, size_t ws_size,
                              hipStream_t stream) {
    const int* exs = (const int*)d_in[0];
    const int* cls = (const int*)d_in[1];
    const void* E_raw     = d_in[2];
    const void* WiF_raw   = d_in[3];
    const void* WhF_raw   = d_in[4];
    const void* bF_raw    = d_in[5];
    const void* WiB_raw   = d_in[6];
    const void* WhB_raw   = d_in[7];
    const void* bB_raw    = d_in[8];
    const void* Wattn_raw = d_in[9];
    const void* Wcomp_raw = d_in[10];
    const void* bcomp_raw = d_in[11];
    const void* vWi_raw   = d_in[12];
    const void* vWh_raw   = d_in[13];
    const void* vb_raw    = d_in[14];
    const void* fe_raw    = d_in[15];
    const int* actions = (const int*)d_in[16];
    (void)in_sizes; (void)n_in; (void)out_size; (void)ws_size;

    char* w = (char*)d_ws;
    size_t off = 0;
    auto take = [&](size_t bytes) -> char* {
        char* p = w + off;
        off = (off + bytes + 255) & ~(size_t)255;
        return p;
    };
    __hip_bfloat16* WhT    = (__hip_bfloat16*)take(2ull * 2048 * 512 * 2);
    __hip_bfloat16* WiT    = (__hip_bfloat16*)take(2ull * 2048 * 256 * 2);
    __hip_bfloat16* vWhT   = (__hip_bfloat16*)take(4096ull * 1024 * 2);
    __hip_bfloat16* vWiT   = (__hip_bfloat16*)take(4096ull * 1024 * 2);
    __hip_bfloat16* WattnT = (__hip_bfloat16*)take(1024ull * 1024 * 2);
    __hip_bfloat16* WcT    = (__hip_bfloat16*)take(64ull * 2048 * 2);
    __hip_bfloat16* Ebf    = (__hip_bfloat16*)take(128ull * 128 * 2);
    __hip_bfloat16* febf   = (__hip_bfloat16*)take(32ull * 1024 * 2);
    float* bFf   = (float*)take(2048 * 4);
    float* bBf   = (float*)take(2048 * 4);
    float* bcf   = (float*)take(64 * 4);
    float* vbf   = (float*)take(4096 * 4);
    float* Gtab  = (float*)take(4ull * 128 * 2048 * 4);
    float* VX    = (float*)take(32ull * 4096 * 4);
    __hip_bfloat16* hEnc = (__hip_bfloat16*)take(2ull * 2 * 1024 * 512 * 2); // [buf][dir][1024][512]
    float* cEnc = (float*)take(2ull * 1024 * 512 * 4);
    __hip_bfloat16* hAll = (__hip_bfloat16*)take(33ull * 256 * 1024 * 2);    // h_0..h_32
    float* cDec = (float*)take(256ull * 1024 * 4);
    float* qall = (float*)take(32ull * 256 * 1024 * 4);
    float* nllT = (float*)take(32ull * 256 * 4);
    int*   mode = (int*)take(256);
    unsigned char* ctx8  = (unsigned char*)take(64ull * 1024 * 1024);  // fp8 [l][b4n][e]
    unsigned char* ctxT8 = (unsigned char*)take(64ull * 1024 * 1024);  // fp8 [b4n][e][l]

    (void)hipMemsetAsync(hEnc, 0, 2ull * 1024 * 512 * 2, stream);  // h buf0, both dirs
    (void)hipMemsetAsync(cEnc, 0, 2ull * 1024 * 512 * 4, stream);

    kdetect<<<1, 128, 0, stream>>>((const unsigned int*)E_raw, mode);

    // fused dtype conversions (was 6 launches)
    {
        CvtArgs ca;
        ca.src[0] = E_raw;     ca.dst[0] = Ebf;  ca.n[0] = 128 * 128;  ca.bf16out[0] = 1;
        ca.src[1] = fe_raw;    ca.dst[1] = febf; ca.n[1] = 32 * 1024;  ca.bf16out[1] = 1;
        ca.src[2] = bF_raw;    ca.dst[2] = bFf;  ca.n[2] = 2048;       ca.bf16out[2] = 0;
        ca.src[3] = bB_raw;    ca.dst[3] = bBf;  ca.n[3] = 2048;       ca.bf16out[3] = 0;
        ca.src[4] = bcomp_raw; ca.dst[4] = bcf;  ca.n[4] = 64;         ca.bf16out[4] = 0;
        ca.src[5] = vb_raw;    ca.dst[5] = vbf;  ca.n[5] = 4096;       ca.bf16out[5] = 0;
        kcvt_all<<<dim3(128, 6), 256, 0, stream>>>(ca, mode);
    }

    // fused transposes (was 8 launches)
    {
        TransArgs ta;
        ta.src[0] = WhF_raw;   ta.dst[0] = WhT;              ta.R[0] = 512;  ta.C[0] = 2048;
        ta.src[1] = WhB_raw;   ta.dst[1] = WhT + 2048 * 512; ta.R[1] = 512;  ta.C[1] = 2048;
        ta.src[2] = WiF_raw;   ta.dst[2] = WiT;              ta.R[2] = 256;  ta.C[2] = 2048;
        ta.src[3] = WiB_raw;   ta.dst[3] = WiT + 2048 * 256; ta.R[3] = 256;  ta.C[3] = 2048;
        ta.src[4] = vWh_raw;   ta.dst[4] = vWhT;             ta.R[4] = 1024; ta.C[4] = 4096;
        ta.src[5] = vWi_raw;   ta.dst[5] = vWiT;             ta.R[5] = 1024; ta.C[5] = 4096;
        ta.src[6] = Wattn_raw; ta.dst[6] = WattnT;           ta.R[6] = 1024; ta.C[6] = 1024;
        ta.src[7] = Wcomp_raw; ta.dst[7] = WcT;              ta.R[7] = 2048; ta.C[7] = 64;
        ktrans_all<<<dim3(64, 32, 8), 256, 0, stream>>>(ta, mode);
    }

    kprep_gtab<<<256, 256, 0, stream>>>(Ebf, WiT, bFf, bBf, Gtab);
    kprep_vx<<<32, 256, 0, stream>>>(febf, vWiT, vbf, VX);

    const size_t HB = 2ull * 1024 * 512;
    for (int t = 0; t < 64; t++) {
        kenc_step<<<512, 256, 0, stream>>>(t, WhT, Gtab, exs, cls,
                                           hEnc + (size_t)(t & 1) * HB,
                                           hEnc + (size_t)((t + 1) & 1) * HB,
                                           cEnc, ctx8);
    }
    ktrans8<<<dim3(1024, 16), 256, 0, stream>>>(ctx8, ctxT8);
    kinit_dec<<<1024, 256, 0, stream>>>(hEnc, cEnc, hAll, cDec);

    const size_t HD = 256ull * 1024;
    for (int t = 0; t < 32; t++) {
        kdec_gemm<<<256, 256, 0, stream>>>(t, vWhT, WattnT, VX,
                                           hAll + (size_t)t * HD,
                                           hAll + (size_t)(t + 1) * HD,
                                           cDec, qall + (size_t)t * HD);
    }
    kattn_mfma<<<256, 512, 0, stream>>>(qall, ctx8, ctxT8, hAll, WcT, bcf,
                                        actions, nllT);
    kfinal<<<1, 256, 0, stream>>>(nllT, d_out, mode);
}